// Round 1
// baseline (2465.388 us; speedup 1.0000x reference)
//
#include <hip/hip_runtime.h>

// Detect (SSD post-process): softmax -> decode -> per-batch NMS scan.
// B=128 P=8732 C=21 TOP_K=200 VAR0=0.1 VAR1=0.2 CONF=0.01 NMS=0.45
//
// Strategy: all decision-relevant math in fp64 so discrete decisions
// (argmax order, score>0.01, iou>0.45) match any correct f64 reference
// (margins ~1e-4 >> f64 error ~1e-16). Outputs rounded to f32.
//
// ws layout (needs 49,178,624 B):
//   [0)                boxes_d  : double[B*P*4]  (35,766,272 B)
//   [35,766,272)       scores_d : double[B*P]    ( 8,941,568 B)
//   [44,707,840)       cls      : int[B*P]       ( 4,470,784 B)

#define BATCH 128
#define NPRIOR 8732
#define NCLS 21
#define TOPK 200
#define BLK2 512
#define NCHUNK 18  // ceil(8732/512)

__global__ __launch_bounds__(256) void prep_kernel(
    const float* __restrict__ loc, const float* __restrict__ conf,
    const float* __restrict__ prior, double* __restrict__ boxes_d,
    double* __restrict__ scores_d, int* __restrict__ cls_o) {
  __shared__ __align__(16) float srow[256 * NCLS];  // 21504 B
  const int tid = threadIdx.x;
  const long long R0 = (long long)blockIdx.x * 256;

  // Stage 256 conf rows (256*21 floats) coalesced via float4.
  // R0*21*4 bytes = blockIdx*21504, 16B-aligned; 256*21/4 = 1344 float4.
  const float4* src = (const float4*)(conf + R0 * NCLS);
  float4* dst = (float4*)srow;
  for (int k = tid; k < 1344; k += 256) dst[k] = src[k];
  __syncthreads();

  const float* row = srow + tid * NCLS;
  // softmax in f64: m = max, e = exp(x-m), score = max_{j>=1} e_j / sum
  double m = (double)row[0];
#pragma unroll
  for (int j = 1; j < NCLS; ++j) m = fmax(m, (double)row[j]);
  double sum = 0.0, best = -1.0;
  int bi = 1;
#pragma unroll
  for (int j = 0; j < NCLS; ++j) {
    double ej = exp((double)row[j] - m);
    sum += ej;
    if (j >= 1 && ej > best) { best = ej; bi = j; }  // first-index tiebreak
  }
  double score = best / sum;
  double s = (score > 0.01) ? score : -1.0;

  const long long r = R0 + tid;
  scores_d[r] = s;
  cls_o[r] = bi - 1;

  // decode in f64
  const int p = (int)(r % NPRIOR);
  float4 l = ((const float4*)loc)[r];
  float4 pr = ((const float4*)prior)[p];
  double cx = (double)pr.x + (double)l.x * 0.1 * (double)pr.z;
  double cy = (double)pr.y + (double)l.y * 0.1 * (double)pr.w;
  double w = (double)pr.z * exp((double)l.z * 0.2);
  double h = (double)pr.w * exp((double)l.w * 0.2);
  double* bd = boxes_d + r * 4;
  bd[0] = cx - w * 0.5;
  bd[1] = cy - h * 0.5;
  bd[2] = cx + w * 0.5;
  bd[3] = cy + h * 0.5;
}

__global__ __launch_bounds__(BLK2) void nms_kernel(
    const double* __restrict__ boxes_d, const double* __restrict__ scores_d,
    const int* __restrict__ cls_i, float* __restrict__ out) {
  __shared__ int cls_s[NPRIOR];     // 34928 B
  __shared__ double wval[8];
  __shared__ int widx[8];
  __shared__ double wbox[6];        // si, x1, y1, x2, y2, area
  __shared__ int wcls_s;

  const int tid = threadIdx.x;
  const int b = blockIdx.x;
  const double* sc = scores_d + (long long)b * NPRIOR;
  const double* bx = boxes_d + (long long)b * NPRIOR * 4;
  float* outb = out + (long long)b * TOPK * 6;

  for (int k = tid; k < NPRIOR; k += BLK2)
    cls_s[k] = cls_i[(long long)b * NPRIOR + k];

  // Per-thread owned elements: p = tid + k*512, k in [0,18). Cached local max.
  unsigned int alive = 0u;
  double lmax = -1e300;
  int lidx = 0x7fffffff;
#pragma unroll
  for (int k = 0; k < NCHUNK; ++k) {
    int p = tid + k * BLK2;
    if (p < NPRIOR) {
      double s0 = sc[p];
      if (s0 > 0.0) {
        alive |= (1u << k);
        if (s0 > lmax) { lmax = s0; lidx = p; }
      }
    }
  }
  __syncthreads();

  int it = 0;
  for (; it < TOPK; ++it) {
    // block argmax with first-index tiebreak
    double v = lmax;
    int ix = lidx;
#pragma unroll
    for (int off = 32; off; off >>= 1) {
      double ov = __shfl_down(v, off);
      int oi = __shfl_down(ix, off);
      if (ov > v || (ov == v && oi < ix)) { v = ov; ix = oi; }
    }
    if ((tid & 63) == 0) { wval[tid >> 6] = v; widx[tid >> 6] = ix; }
    __syncthreads();
    if (tid == 0) {
      double bv = wval[0];
      int bix = widx[0];
#pragma unroll
      for (int w2 = 1; w2 < 8; ++w2) {
        double ov = wval[w2];
        int oi = widx[w2];
        if (ov > bv || (ov == bv && oi < bix)) { bv = ov; bix = oi; }
      }
      wbox[0] = bv;
      if (bv > 0.0) {
        double x1 = bx[(long long)bix * 4 + 0];
        double y1 = bx[(long long)bix * 4 + 1];
        double x2 = bx[(long long)bix * 4 + 2];
        double y2 = bx[(long long)bix * 4 + 3];
        int ci = cls_s[bix];
        wbox[1] = x1; wbox[2] = y1; wbox[3] = x2; wbox[4] = y2;
        wbox[5] = (x2 - x1) * (y2 - y1);
        wcls_s = ci;
        outb[it * 6 + 0] = (float)x1;
        outb[it * 6 + 1] = (float)y1;
        outb[it * 6 + 2] = (float)x2;
        outb[it * 6 + 3] = (float)y2;
        outb[it * 6 + 4] = (float)bv;
        outb[it * 6 + 5] = (float)ci;
      }
    }
    __syncthreads();
    double si = wbox[0];
    if (si <= 0.0) break;  // all remaining are -1 forever -> zero rows
    double X1 = wbox[1], Y1 = wbox[2], X2 = wbox[3], Y2 = wbox[4];
    double AI = wbox[5];
    int ci = wcls_s;

    // suppress same-class alive boxes with IoU > 0.45 (includes pick itself)
    bool lost = false;
    unsigned int a = alive;
    while (a) {
      int k = __builtin_ctz(a);
      a &= a - 1;
      int p = tid + k * BLK2;
      if (cls_s[p] == ci) {
        const double* bp = bx + (long long)p * 4;
        double bx1 = bp[0], by1 = bp[1], bx2 = bp[2], by2 = bp[3];
        double ix1 = fmax(X1, bx1), iy1 = fmax(Y1, by1);
        double ix2 = fmin(X2, bx2), iy2 = fmin(Y2, by2);
        double inter = fmax(ix2 - ix1, 0.0) * fmax(iy2 - iy1, 0.0);
        double areas = (bx2 - bx1) * (by2 - by1);
        double iou = inter / (AI + areas - inter);
        if (iou > 0.45) {
          alive &= ~(1u << k);
          if (p == lidx) lost = true;
        }
      }
    }
    if (lost) {  // cached max was suppressed: rescan owned alive elements
      lmax = -1e300;
      lidx = 0x7fffffff;
      unsigned int a2 = alive;
      while (a2) {
        int k = __builtin_ctz(a2);
        a2 &= a2 - 1;
        int p = tid + k * BLK2;
        double s0 = sc[p];
        if (s0 > lmax) { lmax = s0; lidx = p; }
      }
    }
  }
  // zero-fill rows [it, TOPK)
  for (int k = it * 6 + tid; k < TOPK * 6; k += BLK2) outb[k] = 0.0f;
}

extern "C" void kernel_launch(void* const* d_in, const int* in_sizes, int n_in,
                              void* d_out, int out_size, void* d_ws,
                              size_t ws_size, hipStream_t stream) {
  const float* loc = (const float*)d_in[0];    // B*P*4
  const float* conf = (const float*)d_in[1];   // B*P*21
  const float* prior = (const float*)d_in[2];  // P*4
  float* out = (float*)d_out;                  // B*200*6

  char* ws = (char*)d_ws;
  double* boxes_d = (double*)ws;                                  // 35,766,272 B
  double* scores_d = (double*)(ws + 35766272ULL);                 //  8,941,568 B
  int* cls_o = (int*)(ws + 35766272ULL + 8941568ULL);             //  4,470,784 B
  // total ws need: 49,178,624 B (assumed <= ws_size)

  const int nrows_blocks = (BATCH * NPRIOR) / 256;  // 4366, exact
  prep_kernel<<<nrows_blocks, 256, 0, stream>>>(loc, conf, prior, boxes_d,
                                                scores_d, cls_o);
  nms_kernel<<<BATCH, BLK2, 0, stream>>>(boxes_d, scores_d, cls_o, out);
}

// Round 2
// 569.343 us; speedup vs baseline: 4.3302x; 4.3302x over previous
//
#include <hip/hip_runtime.h>

// Detect (SSD post-process): softmax/decode -> per-batch sorted-scan NMS.
// B=128 P=8732 C=21 TOP_K=200 VAR0=0.1 VAR1=0.2 CONF=0.01 NMS=0.45
//
// Equivalence: reference's 200x argmax-and-suppress == scan candidates in
// (score desc, index asc) order, accept iff no previously-ACCEPTED same-class
// box has IoU>0.45, stop at 200 accepted; remaining rows zero.
//
// Numerics: f32 mirroring np op order (fp contract off, exp via f64->f32 =
// correctly rounded), so decision margins match the np f32 reference to ~1 ulp.
//
// ws: boxes float4[B*P] (17,883,136 B) | keys u64[B*P] (8,941,568 B)

#define BATCH 128
#define NPRIOR 8732
#define NCLS 21
#define TOPK 200
#define NSORT 16384
#define SBLK 1024

__global__ __launch_bounds__(256) void prep_kernel(
    const float* __restrict__ loc, const float* __restrict__ conf,
    const float* __restrict__ prior, float4* __restrict__ boxes,
    unsigned long long* __restrict__ keys) {
#pragma clang fp contract(off)
  __shared__ __align__(16) float srow[256 * NCLS];  // 21504 B
  const int tid = threadIdx.x;
  const long long R0 = (long long)blockIdx.x * 256;

  // Stage 256 conf rows coalesced (blockIdx*21504 B is 16B-aligned).
  const float4* src = (const float4*)(conf + R0 * NCLS);
  float4* dst = (float4*)srow;
  for (int k = tid; k < 1344; k += 256) dst[k] = src[k];
  __syncthreads();

  const float* row = srow + tid * NCLS;
  // softmax mirrored: m=max; e=exp(x-m); sum; p_j=e_j/sum; max+first-argmax
  float m = row[0];
#pragma unroll
  for (int j = 1; j < NCLS; ++j) m = fmaxf(m, row[j]);
  float e[NCLS];
  float sum = 0.0f;
#pragma unroll
  for (int j = 0; j < NCLS; ++j) {
    e[j] = (float)exp((double)(row[j] - m));  // correctly-rounded f32 exp
    sum += e[j];
  }
  float best = -1.0f;
  int bi = 1;
#pragma unroll
  for (int j = 1; j < NCLS; ++j) {
    float p = e[j] / sum;
    if (p > best) { best = p; bi = j; }  // strict > : first-index tiebreak
  }

  const long long r = R0 + tid;
  const int p = (int)(r % NPRIOR);

  unsigned long long key = 0ULL;
  if (best > 0.01f) {
    unsigned hi = __float_as_uint(best);  // positive float: uint-order == float-order
    unsigned lo = ((unsigned)(16383 - p) << 16) | (unsigned)(bi - 1);
    key = ((unsigned long long)hi << 32) | lo;
  }
  keys[r] = key;

  // decode mirrored: xy = p_xy + (l_xy*0.1)*p_wh ; wh = p_wh * exp(l_wh*0.2)
  float4 l = ((const float4*)loc)[r];
  float4 pr = ((const float4*)prior)[p];
  float cx = pr.x + (l.x * 0.1f) * pr.z;
  float cy = pr.y + (l.y * 0.1f) * pr.w;
  float w = pr.z * (float)exp((double)(l.z * 0.2f));
  float h = pr.w * (float)exp((double)(l.w * 0.2f));
  boxes[r] = make_float4(cx - w * 0.5f, cy - h * 0.5f, cx + w * 0.5f, cy + h * 0.5f);
}

__global__ __launch_bounds__(SBLK, 1) void nms_kernel(
    const float4* __restrict__ boxes, const unsigned long long* __restrict__ keys,
    float* __restrict__ out) {
  __shared__ unsigned long long K[NSORT];  // 131072 B (gfx950: 160KB/WG ok)
  __shared__ float ax1[TOPK], ay1[TOPK], ax2[TOPK], ay2[TOPK], aar[TOPK];
  __shared__ int acl[TOPK];

  const int tid = threadIdx.x;
  const int b = blockIdx.x;
  const unsigned long long* kb = keys + (long long)b * NPRIOR;

  for (int i = tid; i < NSORT; i += SBLK) K[i] = (i < NPRIOR) ? kb[i] : 0ULL;
  __syncthreads();

  // bitonic sort, descending
  for (int k = 2; k <= NSORT; k <<= 1) {
    for (int j = k >> 1; j > 0; j >>= 1) {
      for (int i = tid; i < NSORT; i += SBLK) {
        int ixj = i ^ j;
        if (ixj > i) {
          unsigned long long a = K[i], c = K[ixj];
          if (((i & k) == 0) ? (a < c) : (a > c)) { K[i] = c; K[ixj] = a; }
        }
      }
      __syncthreads();
    }
  }
  __syncthreads();

  float* outb = out + (long long)b * (TOPK * 6);
  if (tid >= 64) return;  // single-wave scan; no barriers below
  const int lane = tid;
  const float4* bxb = boxes + (long long)b * NPRIOR;

  int nA = 0;
  bool done = false;
  for (int c0 = 0; c0 < NSORT && nA < TOPK && !done; c0 += 64) {
    unsigned long long key = K[c0 + lane];
    bool valid = (key != 0ULL);
    float sc = __uint_as_float((unsigned)(key >> 32));
    unsigned lo = (unsigned)key;
    int p = 16383 - (int)((lo >> 16) & 0x3FFFu);
    int cl = (int)(lo & 0xFFFFu);
    float4 bx = make_float4(0.f, 0.f, 0.f, 0.f);
    if (valid) bx = bxb[p];
    float ar = (bx.z - bx.x) * (bx.w - bx.y);

    // pre-check vs boxes accepted in earlier chunks
    bool sup = false;
    for (int a2 = 0; a2 < nA; ++a2) {
      if (acl[a2] == cl) {
        float ix1 = fmaxf(ax1[a2], bx.x), iy1 = fmaxf(ay1[a2], bx.y);
        float ix2 = fminf(ax2[a2], bx.z), iy2 = fminf(ay2[a2], bx.w);
        float inter = fmaxf(ix2 - ix1, 0.f) * fmaxf(iy2 - iy1, 0.f);
        float iou = inter / (aar[a2] + ar - inter);
        if (iou > 0.45f) sup = true;
      }
    }

    // sequential resolve within chunk (shuffle broadcast, no barriers)
    for (int c = 0; c < 64; ++c) {
      if (!__shfl(valid ? 1 : 0, c)) { done = true; break; }  // sorted: rest invalid
      if (__shfl(sup ? 1 : 0, c)) continue;                   // suppressed: skip
      float X1 = __shfl(bx.x, c), Y1 = __shfl(bx.y, c);
      float X2 = __shfl(bx.z, c), Y2 = __shfl(bx.w, c);
      float AR = __shfl(ar, c), SC = __shfl(sc, c);
      int CL = __shfl(cl, c);
      if (lane == 0) {
        float* o = outb + nA * 6;
        o[0] = X1; o[1] = Y1; o[2] = X2; o[3] = Y2; o[4] = SC; o[5] = (float)CL;
        ax1[nA] = X1; ay1[nA] = Y1; ax2[nA] = X2; ay2[nA] = Y2;
        aar[nA] = AR; acl[nA] = CL;
      }
      nA++;
      if (nA == TOPK) break;
      if (lane > c && !sup && cl == CL) {  // update own candidate vs new accept
        float ix1 = fmaxf(X1, bx.x), iy1 = fmaxf(Y1, bx.y);
        float ix2 = fminf(X2, bx.z), iy2 = fminf(Y2, bx.w);
        float inter = fmaxf(ix2 - ix1, 0.f) * fmaxf(iy2 - iy1, 0.f);
        float iou = inter / (AR + ar - inter);
        if (iou > 0.45f) sup = true;
      }
    }
  }
  // zero-fill rows [nA, TOPK)
  for (int k2 = nA * 6 + lane; k2 < TOPK * 6; k2 += 64) outb[k2] = 0.0f;
}

extern "C" void kernel_launch(void* const* d_in, const int* in_sizes, int n_in,
                              void* d_out, int out_size, void* d_ws,
                              size_t ws_size, hipStream_t stream) {
  const float* loc = (const float*)d_in[0];    // B*P*4
  const float* conf = (const float*)d_in[1];   // B*P*21
  const float* prior = (const float*)d_in[2];  // P*4
  float* out = (float*)d_out;                  // B*200*6

  char* ws = (char*)d_ws;
  float4* boxes = (float4*)ws;                                   // 17,883,136 B
  unsigned long long* keys = (unsigned long long*)(ws + 17883136ULL);  // 8,941,568 B

  const int nrows_blocks = (BATCH * NPRIOR) / 256;  // 4366 exact
  prep_kernel<<<nrows_blocks, 256, 0, stream>>>(loc, conf, prior, boxes, keys);
  nms_kernel<<<BATCH, SBLK, 0, stream>>>(boxes, keys, out);
}

// Round 3
// 386.639 us; speedup vs baseline: 6.3765x; 1.4725x over previous
//
#include <hip/hip_runtime.h>

// Detect (SSD post-process): softmax/decode -> per-batch radix-select + sort + scan NMS.
// B=128 P=8732 C=21 TOP_K=200 VAR0=0.1 VAR1=0.2 CONF=0.01 NMS=0.45
//
// Equivalence: reference's 200x argmax-and-suppress == scan candidates in
// (score desc, index asc) order, accept iff no previously-ACCEPTED same-class
// box has IoU>0.45, stop at 200 accepted; remaining rows zero.
// Only ~220 sorted candidates are ever examined -> select top ~1024 by score
// via 4096-bin radix histogram, sort only those. Round loop w/ shrinking key
// upper-bound keeps it correct even under extreme suppression.
//
// Numerics: f64 score/decode path (R1-passing op order); libm exp replaced by
// Cody-Waite + deg-11 Horner (rel err <1e-14 << 1e-7 decision margins).
//
// ws: boxes float4[B*P] (17,883,136 B) | keys u64[B*P] (8,941,568 B)

#define BATCH 128
#define NPRIOR 8732
#define NCLS 21
#define TOPK 200
#define T2 256
#define NC 1024   // selection target per round
#define CAP 4096  // selection buffer capacity
#define NBIN 4096

typedef unsigned long long u64;

__device__ __forceinline__ double exp_fast(double x) {
  // exp for |x| < ~50, rel err < 1e-14: n = rint(x*log2e); r = x - n*ln2
  const double LOG2E = 1.4426950408889634;
  const double LN2_HI = 6.93147180369123816490e-01;
  const double LN2_LO = 1.90821492927058770002e-10;
  double n = rint(x * LOG2E);
  double r = fma(-n, LN2_HI, x);
  r = fma(-n, LN2_LO, r);
  double p = 2.505210838544172e-08;   // 1/11!
  p = fma(p, r, 2.755731922398589e-07);   // 1/10!
  p = fma(p, r, 2.7557319223985893e-06);  // 1/9!
  p = fma(p, r, 2.48015873015873e-05);    // 1/8!
  p = fma(p, r, 1.984126984126984e-04);   // 1/7!
  p = fma(p, r, 1.388888888888889e-03);   // 1/6!
  p = fma(p, r, 8.333333333333333e-03);   // 1/5!
  p = fma(p, r, 4.1666666666666664e-02);  // 1/4!
  p = fma(p, r, 1.6666666666666666e-01);  // 1/3!
  p = fma(p, r, 0.5);
  p = fma(p, r, 1.0);
  p = fma(p, r, 1.0);
  return ldexp(p, (int)n);
}

__global__ __launch_bounds__(256) void prep_kernel(
    const float* __restrict__ loc, const float* __restrict__ conf,
    const float* __restrict__ prior, float4* __restrict__ boxes,
    u64* __restrict__ keys) {
  __shared__ __align__(16) float srow[256 * NCLS];  // 21504 B
  const int tid = threadIdx.x;
  const long long R0 = (long long)blockIdx.x * 256;

  // Stage 256 conf rows coalesced (blockIdx*21504 B is 16B-aligned).
  const float4* src = (const float4*)(conf + R0 * NCLS);
  float4* dst = (float4*)srow;
  for (int k = tid; k < 1344; k += 256) dst[k] = src[k];
  __syncthreads();

  const float* row = srow + tid * NCLS;
  double m = (double)row[0];
#pragma unroll
  for (int j = 1; j < NCLS; ++j) m = fmax(m, (double)row[j]);
  double sum = 0.0, best = -1.0;
  int bi = 1;
#pragma unroll
  for (int j = 0; j < NCLS; ++j) {
    double ej = exp_fast((double)row[j] - m);
    sum += ej;
    if (j >= 1 && ej > best) { best = ej; bi = j; }  // first-index tiebreak
  }
  double score = best / sum;

  const long long r = R0 + tid;
  const int p = (int)(r % NPRIOR);

  u64 key = 0ULL;
  if (score > 0.01) {
    float sf = (float)score;  // positive: uint order == float order
    unsigned lo = ((unsigned)(16383 - p) << 16) | (unsigned)(bi - 1);
    key = ((u64)__float_as_uint(sf) << 32) | lo;
  }
  keys[r] = key;

  // decode (R1-passing f64 op order)
  float4 l = ((const float4*)loc)[r];
  float4 pr = ((const float4*)prior)[p];
  double cx = (double)pr.x + (double)l.x * 0.1 * (double)pr.z;
  double cy = (double)pr.y + (double)l.y * 0.1 * (double)pr.w;
  double w = (double)pr.z * exp_fast((double)l.z * 0.2);
  double h = (double)pr.w * exp_fast((double)l.w * 0.2);
  boxes[r] = make_float4((float)(cx - w * 0.5), (float)(cy - h * 0.5),
                         (float)(cx + w * 0.5), (float)(cy + h * 0.5));
}

__global__ __launch_bounds__(T2, 1) void nms_kernel(
    const float4* __restrict__ boxes, const u64* __restrict__ keys,
    float* __restrict__ out) {
  __shared__ u64 Ks[NPRIOR];    // 69,856 B
  __shared__ u64 buf[CAP];      // 32,768 B
  __shared__ int hist[NBIN];    // 16,384 B
  __shared__ int scs[T2];       //  1,024 B
  __shared__ float ax1[TOPK], ay1[TOPK], ax2[TOPK], ay2[TOPK], aar[TOPK];
  __shared__ int acl[TOPK];
  __shared__ int sh_cut, sh_M, sh_cnt, sh_nA;
  __shared__ u64 sh_ub;

  const int tid = threadIdx.x;
  const int b = blockIdx.x;
  const u64* kb = keys + (long long)b * NPRIOR;
  const float4* bxb = boxes + (long long)b * NPRIOR;
  float* outb = out + (long long)b * (TOPK * 6);

  for (int i = tid; i < NPRIOR; i += T2) Ks[i] = kb[i];
  if (tid == 0) { sh_nA = 0; sh_ub = ~0ULL; }
  __syncthreads();

  while (true) {
    // --- level-1 histogram of top 12 key bits, restricted to keys < ubound
    for (int i = tid; i < NBIN; i += T2) hist[i] = 0;
    __syncthreads();
    const u64 ub = sh_ub;
    for (int i = tid; i < NPRIOR; i += T2) {
      u64 k = Ks[i];
      if (k && k < ub) atomicAdd(&hist[(int)(k >> 52)], 1);
    }
    __syncthreads();
    // --- suffix sums: chunk of 16 bins per thread, then Hillis-Steele
    const int base = tid * 16;
    int cs = 0;
    for (int j = 0; j < 16; ++j) cs += hist[base + j];
    scs[tid] = cs;
    __syncthreads();
    for (int off = 1; off < T2; off <<= 1) {
      int v = (tid + off < T2) ? scs[tid + off] : 0;
      __syncthreads();
      scs[tid] += v;
      __syncthreads();
    }
    const int total = scs[0];  // remaining candidates below ubound
    if (tid == 0) { sh_M = 0; sh_cnt = 0; }
    __syncthreads();
    if (total > 0) {
      const int target = total < NC ? total : NC;
      int mysuf = scs[tid];
      int nextsuf = (tid + 1 < T2) ? scs[tid + 1] : 0;
      if (mysuf >= target && nextsuf < target) {  // unique winner thread
        int acc = nextsuf, c = base, M = 0;
        for (int bn = base + 15; bn >= base; --bn) {
          acc += hist[bn];
          if (acc >= target) { c = bn; M = acc; break; }
        }
        if (M > CAP) {  // pathological fat bin: take fewer this round
          if (M - hist[c] > 0) { M -= hist[c]; c += 1; } else { M = CAP; }
        }
        sh_cut = c; sh_M = M;
      }
    }
    __syncthreads();
    const int M = sh_M;
    if (M == 0) break;  // nothing remains
    const int cut = sh_cut;
    // --- compact selected keys (order irrelevant; sort is total on unique keys)
    for (int i = tid; i < NPRIOR; i += T2) {
      u64 k = Ks[i];
      if (k && k < ub && (int)(k >> 52) >= cut) {
        int pos = atomicAdd(&sh_cnt, 1);
        if (pos < CAP) buf[pos] = k;
      }
    }
    __syncthreads();
    int Mr = sh_cnt; if (Mr > CAP) Mr = CAP;
    int np2 = 64; while (np2 < Mr) np2 <<= 1;
    for (int i = Mr + tid; i < np2; i += T2) buf[i] = 0;
    __syncthreads();
    // --- bitonic sort descending, np2 <= 4096
    for (int k2 = 2; k2 <= np2; k2 <<= 1) {
      for (int j = k2 >> 1; j > 0; j >>= 1) {
        for (int i = tid; i < np2; i += T2) {
          int ixj = i ^ j;
          if (ixj > i) {
            u64 a = buf[i], c = buf[ixj];
            if (((i & k2) == 0) ? (a < c) : (a > c)) { buf[i] = c; buf[ixj] = a; }
          }
        }
        __syncthreads();
      }
    }
    // --- single-wave sorted scan (no barriers inside)
    if (tid < 64) {
      const int lane = tid;
      int nA = sh_nA;
      for (int c0 = 0; c0 < Mr && nA < TOPK; c0 += 64) {
        int lim = Mr - c0; if (lim > 64) lim = 64;
        bool inb = lane < lim;
        u64 key = inb ? buf[c0 + lane] : 0ULL;
        float sc = __uint_as_float((unsigned)(key >> 32));
        unsigned lo = (unsigned)key;
        int p = 16383 - (int)((lo >> 16) & 0x3FFFu);
        int cl = (int)(lo & 0xFFFFu);
        float4 bx = make_float4(0.f, 0.f, 0.f, 0.f);
        if (inb) bx = bxb[p];
        float ar = (bx.z - bx.x) * (bx.w - bx.y);
        // pre-check vs already-accepted (earlier chunks/rounds)
        bool sup = !inb;
        for (int a2 = 0; a2 < nA; ++a2) {
          if (acl[a2] == cl) {
            float ix1 = fmaxf(ax1[a2], bx.x), iy1 = fmaxf(ay1[a2], bx.y);
            float ix2 = fminf(ax2[a2], bx.z), iy2 = fminf(ay2[a2], bx.w);
            float inter = fmaxf(ix2 - ix1, 0.f) * fmaxf(iy2 - iy1, 0.f);
            float iou = inter / (aar[a2] + ar - inter);
            if (iou > 0.45f) sup = true;
          }
        }
        // sequential resolve within chunk via shuffle broadcast
        for (int c = 0; c < lim; ++c) {
          if (__shfl(sup ? 1 : 0, c)) continue;
          float X1 = __shfl(bx.x, c), Y1 = __shfl(bx.y, c);
          float X2 = __shfl(bx.z, c), Y2 = __shfl(bx.w, c);
          float AR = __shfl(ar, c), SC = __shfl(sc, c);
          int CL = __shfl(cl, c);
          if (lane == 0) {
            float* o = outb + nA * 6;
            o[0] = X1; o[1] = Y1; o[2] = X2; o[3] = Y2; o[4] = SC; o[5] = (float)CL;
            ax1[nA] = X1; ay1[nA] = Y1; ax2[nA] = X2; ay2[nA] = Y2;
            aar[nA] = AR; acl[nA] = CL;
          }
          nA++;
          if (nA == TOPK) break;
          if (lane > c && !sup && cl == CL) {
            float ix1 = fmaxf(X1, bx.x), iy1 = fmaxf(Y1, bx.y);
            float ix2 = fminf(X2, bx.z), iy2 = fminf(Y2, bx.w);
            float inter = fmaxf(ix2 - ix1, 0.f) * fmaxf(iy2 - iy1, 0.f);
            float iou = inter / (AR + ar - inter);
            if (iou > 0.45f) sup = true;
          }
        }
      }
      if (lane == 0) { sh_nA = nA; sh_ub = buf[Mr - 1]; }
    }
    __syncthreads();
    if (sh_nA >= TOPK) break;
    if (total - Mr <= 0) break;  // candidate pool exhausted
  }
  // zero-fill rows [nA, TOPK)
  const int nAf = sh_nA;
  for (int i = nAf * 6 + tid; i < TOPK * 6; i += T2) outb[i] = 0.0f;
}

extern "C" void kernel_launch(void* const* d_in, const int* in_sizes, int n_in,
                              void* d_out, int out_size, void* d_ws,
                              size_t ws_size, hipStream_t stream) {
  const float* loc = (const float*)d_in[0];    // B*P*4
  const float* conf = (const float*)d_in[1];   // B*P*21
  const float* prior = (const float*)d_in[2];  // P*4
  float* out = (float*)d_out;                  // B*200*6

  char* ws = (char*)d_ws;
  float4* boxes = (float4*)ws;                        // 17,883,136 B
  u64* keys = (u64*)(ws + 17883136ULL);               //  8,941,568 B

  const int nrows_blocks = (BATCH * NPRIOR) / 256;  // 4366 exact
  prep_kernel<<<nrows_blocks, 256, 0, stream>>>(loc, conf, prior, boxes, keys);
  nms_kernel<<<BATCH, T2, 0, stream>>>(boxes, keys, out);
}

// Round 4
// 271.824 us; speedup vs baseline: 9.0698x; 1.4224x over previous
//
#include <hip/hip_runtime.h>

// Detect (SSD post-process). B=128 P=8732 C=21 TOP_K=200 CONF=0.01 NMS=0.45
//
// prep: per-row f64 softmax -> sortable key (40-bit f64 score | 14-bit idx-desc
//       | 5-bit cls). No box decode (nms decodes the ~256 touched rows).
// nms (1 block/batch, 256 thr): 2-level radix select top-256 -> rank sort ->
//       parallel kill-mask matrix -> single uniform serial resolve ->
//       lane-parallel output. Round loop w/ shrinking ubound for correctness
//       under extreme suppression (never triggers on benign data).
//
// Equivalence to reference: scan candidates in (score desc, index asc) order,
// accept iff no previously-ACCEPTED same-class box has IoU>0.45, stop at 200.
//
// ws: keys u64[B*P] = 8,941,568 B

typedef unsigned long long u64;

#define BATCH 128
#define NPRIOR 8732
#define NCLS 21
#define TOPK 200
#define T2 256
#define TARGET 256
#define CAP 384
#define NBIN 4096
#define KW 6  // 384/64 kill-mask words

__device__ __forceinline__ double exp_fast(double x) {
  // exp for |x| < ~50, rel err < 1e-14 (same as R3 -> bit-identical decisions)
  const double LOG2E = 1.4426950408889634;
  const double LN2_HI = 6.93147180369123816490e-01;
  const double LN2_LO = 1.90821492927058770002e-10;
  double n = rint(x * LOG2E);
  double r = fma(-n, LN2_HI, x);
  r = fma(-n, LN2_LO, r);
  double p = 2.505210838544172e-08;
  p = fma(p, r, 2.755731922398589e-07);
  p = fma(p, r, 2.7557319223985893e-06);
  p = fma(p, r, 2.48015873015873e-05);
  p = fma(p, r, 1.984126984126984e-04);
  p = fma(p, r, 1.388888888888889e-03);
  p = fma(p, r, 8.333333333333333e-03);
  p = fma(p, r, 4.1666666666666664e-02);
  p = fma(p, r, 1.6666666666666666e-01);
  p = fma(p, r, 0.5);
  p = fma(p, r, 1.0);
  p = fma(p, r, 1.0);
  return ldexp(p, (int)n);
}

__global__ __launch_bounds__(256) void prep_kernel(
    const float* __restrict__ conf, u64* __restrict__ keys) {
  __shared__ __align__(16) float srow[256 * NCLS];
  const int tid = threadIdx.x;
  const long long R0 = (long long)blockIdx.x * 256;
  const float4* src = (const float4*)(conf + R0 * NCLS);
  float4* dst = (float4*)srow;
  for (int k = tid; k < 1344; k += 256) dst[k] = src[k];
  __syncthreads();

  const float* row = srow + tid * NCLS;
  double m = (double)row[0];
#pragma unroll
  for (int j = 1; j < NCLS; ++j) m = fmax(m, (double)row[j]);
  double sum = 0.0, best = -1.0;
  int bi = 1;
#pragma unroll
  for (int j = 0; j < NCLS; ++j) {
    double ej = exp_fast((double)row[j] - m);
    sum += ej;
    if (j >= 1 && ej > best) { best = ej; bi = j; }  // first-index tiebreak
  }
  double score = best / sum;

  const long long r = R0 + tid;
  const int p = (int)(r % NPRIOR);
  u64 key = 0ULL;
  if (score > 0.01) {
    u64 sb = (u64)__double_as_longlong(score);  // positive: bit order == value order
    key = ((sb >> 24) << 24) | ((u64)(16383 - p) << 10) | (u64)(bi - 1);
  }
  keys[r] = key;
}

__device__ __forceinline__ int suffix_scan_total(int* hist, int* scs, int tid) {
  const int base = tid * 16;
  int cs = 0;
#pragma unroll
  for (int j = 0; j < 16; ++j) cs += hist[base + j];
  scs[tid] = cs;
  __syncthreads();
  for (int off = 1; off < T2; off <<= 1) {
    int v = (tid + off < T2) ? scs[tid + off] : 0;
    __syncthreads();
    scs[tid] += v;
    __syncthreads();
  }
  return scs[0];
}

__global__ __launch_bounds__(T2, 1) void nms_kernel(
    const float* __restrict__ loc, const float* __restrict__ prior,
    const u64* __restrict__ keys, float* __restrict__ out) {
  __shared__ u64 Ks[NPRIOR];          // 69,856 B
  __shared__ int hist[NBIN];          // 16,384 B
  __shared__ int hist2[NBIN];         // 16,384 B
  __shared__ int scs[T2];             //  1,024 B
  __shared__ u64 buf[CAP];            //  3,072 B
  __shared__ u64 buf2[CAP];           //  3,072 B (sorted desc)
  __shared__ float4 cbox[CAP];        //  6,144 B
  __shared__ float car[CAP];          //  1,536 B
  __shared__ int ccl[CAP];            //  1,536 B
  __shared__ u64 KILL[CAP * KW];      // 18,432 B
  __shared__ u64 Ash[KW], KFsh[KW], ACCsh[KW];
  __shared__ float4 abox[TOPK];       //  3,200 B accepted list (multi-round)
  __shared__ float aar[TOPK];
  __shared__ int acl[TOPK];
  __shared__ int sh_c1, sh_base, sh_c2, sh_M, sh_cnt, sh_nA;
  __shared__ u64 sh_ub;
  // total ~139 KB of 160 KB/CU -> 1 block/CU (fine: 128-way batch parallelism)

  const int tid = threadIdx.x;
  const int b = blockIdx.x;
  const u64* kb = keys + (long long)b * NPRIOR;
  const float4* loc4 = ((const float4*)loc) + (long long)b * NPRIOR;
  const float4* pr4 = (const float4*)prior;
  float* outb = out + (long long)b * (TOPK * 6);

  for (int i = tid; i < NPRIOR; i += T2) Ks[i] = kb[i];
  if (tid == 0) { sh_nA = 0; sh_ub = ~0ULL; }
  __syncthreads();

  while (true) {
    for (int i = tid; i < NBIN; i += T2) { hist[i] = 0; hist2[i] = 0; }
    __syncthreads();
    const u64 ub = sh_ub;
    // L1 histogram: top 12 key bits (f64 sign+exponent)
    for (int i = tid; i < NPRIOR; i += T2) {
      u64 k = Ks[i];
      if (k && k < ub) atomicAdd(&hist[(int)(k >> 52)], 1);
    }
    __syncthreads();
    const int total = suffix_scan_total(hist, scs, tid);
    if (tid == 0) { sh_M = 0; sh_cnt = 0; }
    const int target = total < TARGET ? total : TARGET;
    if (total > 0) {
      int mysuf = scs[tid], nextsuf = (tid + 1 < T2) ? scs[tid + 1] : 0;
      if (mysuf >= target && nextsuf < target) {  // unique winner
        int acc = nextsuf;
        for (int bn = tid * 16 + 15; bn >= tid * 16; --bn) {
          acc += hist[bn];
          if (acc >= target) { sh_c1 = bn; sh_base = acc - hist[bn]; break; }
        }
      }
    }
    __syncthreads();
    if (total == 0) break;
    const int c1 = sh_c1, baseA = sh_base;  // baseA = count in bins > c1 (< target)
    // L2 histogram: bits 51..40 of keys in bin c1
    for (int i = tid; i < NPRIOR; i += T2) {
      u64 k = Ks[i];
      if (k && k < ub && (int)(k >> 52) == c1)
        atomicAdd(&hist2[(int)((k >> 40) & 0xFFF)], 1);
    }
    __syncthreads();
    suffix_scan_total(hist2, scs, tid);
    {
      const int need = target - baseA;  // >= 1, and bin c1 holds >= need keys
      int mysuf = scs[tid], nextsuf = (tid + 1 < T2) ? scs[tid + 1] : 0;
      if (mysuf >= need && nextsuf < need) {
        int acc = nextsuf;
        for (int bn = tid * 16 + 15; bn >= tid * 16; --bn) {
          acc += hist2[bn];
          if (acc >= need) {
            int c2 = bn, M = baseA + acc;
            if (M > CAP) {  // fat sub-bin (>=129-way 24-bit score collision): drop it
              M = baseA + (acc - hist2[bn]);
              c2 = bn + 1;
              if (M == 0) { c2 = bn; M = CAP; }  // theoretical; partial take
            }
            sh_c2 = c2; sh_M = M;
            break;
          }
        }
      }
    }
    __syncthreads();
    const int c2 = sh_c2;
    // compact selected keys (prefix >= pivot); order irrelevant (rank sort next)
    for (int i = tid; i < NPRIOR; i += T2) {
      u64 k = Ks[i];
      if (k && k < ub) {
        int b1 = (int)(k >> 52);
        if (b1 > c1 || (b1 == c1 && (int)((k >> 40) & 0xFFF) >= c2)) {
          int pos = atomicAdd(&sh_cnt, 1);
          if (pos < CAP) buf[pos] = k;
        }
      }
    }
    __syncthreads();
    int Mr = sh_cnt; if (Mr > CAP) Mr = CAP;
    // rank sort (keys unique): buf2[rank] = key, descending
    {
      u64 ka = (tid < Mr) ? buf[tid] : 0ULL;
      u64 kb2 = (tid + T2 < Mr) ? buf[tid + T2] : 0ULL;
      int ra = 0, rb = 0;
      for (int i = 0; i < Mr; ++i) {
        u64 k = buf[i];  // LDS broadcast
        ra += (k > ka); rb += (k > kb2);
      }
      if (tid < Mr) buf2[ra] = ka;
      if (tid + T2 < Mr) buf2[rb] = kb2;
    }
    if (tid < KW) { Ash[tid] = 0ULL; KFsh[tid] = 0ULL; }
    __syncthreads();
    const int nA0 = sh_nA;
    // stage candidates: decode boxes on demand (bit-identical f64 ops to R3)
    for (int t = tid; t < Mr; t += T2) {
      u64 k = buf2[t];
      int cl = (int)(k & 0x1FULL);
      int p = 16383 - (int)((k >> 10) & 0x3FFFULL);
      float4 l = loc4[p];
      float4 pr = pr4[p];
      double cx = (double)pr.x + (double)l.x * 0.1 * (double)pr.z;
      double cy = (double)pr.y + (double)l.y * 0.1 * (double)pr.w;
      double w = (double)pr.z * exp_fast((double)l.z * 0.2);
      double h = (double)pr.w * exp_fast((double)l.w * 0.2);
      float x1 = (float)(cx - w * 0.5), y1 = (float)(cy - h * 0.5);
      float x2 = (float)(cx + w * 0.5), y2 = (float)(cy + h * 0.5);
      cbox[t] = make_float4(x1, y1, x2, y2);
      car[t] = (x2 - x1) * (y2 - y1);
      ccl[t] = cl;
    }
    __syncthreads();
    // pre-round suppression (rounds >= 2 only)
    if (nA0 > 0) {
      for (int t = tid; t < Mr; t += T2) {
        float4 my = cbox[t]; float mar = car[t]; int mcl = ccl[t];
        bool sup = false;
        for (int a = 0; a < nA0; ++a) {
          if (acl[a] == mcl) {
            float4 ab = abox[a];
            float ix1 = fmaxf(ab.x, my.x), iy1 = fmaxf(ab.y, my.y);
            float ix2 = fminf(ab.z, my.z), iy2 = fminf(ab.w, my.w);
            float inter = fmaxf(ix2 - ix1, 0.f) * fmaxf(iy2 - iy1, 0.f);
            float iou = inter / (aar[a] + mar - inter);
            if (iou > 0.45f) sup = true;
          }
        }
        if (sup) atomicOr(&Ash[t >> 6], 1ULL << (t & 63));
      }
    }
    // kill-mask matrix: thread t marks all later same-class j with IoU>0.45.
    // Independent of accept decisions -> fully parallel.
    for (int t = tid; t < Mr; t += T2) {
      float4 my = cbox[t]; float mar = car[t]; int mcl = ccl[t];
      bool any = false;
#pragma unroll
      for (int seg = 0; seg < KW; ++seg) {
        int i0 = seg * 64, i1 = i0 + 64;
        if (i1 > Mr) i1 = Mr;
        u64 mm = 0ULL;
        for (int i = i0; i < i1; ++i) {  // uniform i -> LDS broadcast reads
          if (i > t && ccl[i] == mcl) {
            float4 cb = cbox[i];
            float ix1 = fmaxf(my.x, cb.x), iy1 = fmaxf(my.y, cb.y);
            float ix2 = fminf(my.z, cb.z), iy2 = fminf(my.w, cb.w);
            float inter = fmaxf(ix2 - ix1, 0.f) * fmaxf(iy2 - iy1, 0.f);
            float iou = inter / (mar + car[i] - inter);
            if (iou > 0.45f) mm |= 1ULL << (i - i0);
          }
        }
        KILL[(u64)t * KW + seg] = mm;
        any = any || (mm != 0ULL);
      }
      if (any) atomicOr(&KFsh[t >> 6], 1ULL << (t & 63));
    }
    __syncthreads();
    // uniform serial resolve on wave 0 (registers; LDS only on rare kill)
    if (tid < 64) {
      u64 A0, A1, A2, A3, A4, A5;
      {
        u64 v[KW];
#pragma unroll
        for (int w = 0; w < KW; ++w) {
          int rem = Mr - 64 * w;
          u64 vm = (rem >= 64) ? ~0ULL : (rem <= 0 ? 0ULL : ((1ULL << rem) - 1ULL));
          v[w] = vm & ~Ash[w];
        }
        A0 = v[0]; A1 = v[1]; A2 = v[2]; A3 = v[3]; A4 = v[4]; A5 = v[5];
      }
      const u64 KF0 = KFsh[0], KF1 = KFsh[1], KF2 = KFsh[2];
      const u64 KF3 = KFsh[3], KF4 = KFsh[4], KF5 = KFsh[5];
      u64 C0 = 0, C1 = 0, C2 = 0, C3 = 0, C4 = 0, C5 = 0;
      int nacc = nA0;
      bool full = false;
#define KILLUPD(cidx) do { const u64* kc = &KILL[(u64)(cidx) * KW]; \
      A0 &= ~kc[0]; A1 &= ~kc[1]; A2 &= ~kc[2];                     \
      A3 &= ~kc[3]; A4 &= ~kc[4]; A5 &= ~kc[5]; } while (0)
#define RESW(w, Aw, KFw, Cw) if (!full) {                           \
      int lim = Mr - (w) * 64; if (lim > 64) lim = 64;              \
      for (int q = 0; q < lim; ++q) {                               \
        if ((Aw >> q) & 1ULL) {                                     \
          Cw |= 1ULL << q; ++nacc;                                  \
          if (nacc == TOPK) { full = true; break; }                 \
          if ((KFw >> q) & 1ULL) KILLUPD((w) * 64 + q);             \
        } } }
      RESW(0, A0, KF0, C0)
      RESW(1, A1, KF1, C1)
      RESW(2, A2, KF2, C2)
      RESW(3, A3, KF3, C3)
      RESW(4, A4, KF4, C4)
      RESW(5, A5, KF5, C5)
#undef RESW
#undef KILLUPD
      if (tid == 0) {
        ACCsh[0] = C0; ACCsh[1] = C1; ACCsh[2] = C2;
        ACCsh[3] = C3; ACCsh[4] = C4; ACCsh[5] = C5;
        sh_nA = nacc;
        sh_ub = buf2[Mr - 1];  // unselected keys are all strictly below this
      }
    }
    __syncthreads();
    // lane-parallel output of accepted candidates
    for (int t = tid; t < Mr; t += T2) {
      int w = t >> 6, q = t & 63;
      u64 accw = ACCsh[w];
      if ((accw >> q) & 1ULL) {
        int rank = nA0;
#pragma unroll
        for (int w2 = 0; w2 < KW; ++w2)
          if (w2 < w) rank += __popcll(ACCsh[w2]);
        rank += __popcll(accw & ((q == 0) ? 0ULL : ((1ULL << q) - 1ULL)));
        float4 bx = cbox[t];
        float sc = (float)__longlong_as_double((long long)((buf2[t] >> 24) << 24));
        float* o = outb + rank * 6;
        o[0] = bx.x; o[1] = bx.y; o[2] = bx.z; o[3] = bx.w;
        o[4] = sc; o[5] = (float)ccl[t];
        abox[rank] = bx; aar[rank] = car[t]; acl[rank] = ccl[t];
      }
    }
    __syncthreads();
    if (sh_nA >= TOPK) break;
    if (total - Mr <= 0) break;  // pool exhausted
  }
  // zero-fill rows [nA, TOPK)
  const int nAf = sh_nA;
  for (int i = nAf * 6 + tid; i < TOPK * 6; i += T2) outb[i] = 0.0f;
}

extern "C" void kernel_launch(void* const* d_in, const int* in_sizes, int n_in,
                              void* d_out, int out_size, void* d_ws,
                              size_t ws_size, hipStream_t stream) {
  const float* loc = (const float*)d_in[0];    // B*P*4
  const float* conf = (const float*)d_in[1];   // B*P*21
  const float* prior = (const float*)d_in[2];  // P*4
  float* out = (float*)d_out;                  // B*200*6

  u64* keys = (u64*)d_ws;  // 8,941,568 B

  const int nrows_blocks = (BATCH * NPRIOR) / 256;  // 4366 exact
  prep_kernel<<<nrows_blocks, 256, 0, stream>>>(conf, keys);
  nms_kernel<<<BATCH, T2, 0, stream>>>(loc, prior, keys, out);
}

// Round 5
// 246.637 us; speedup vs baseline: 9.9960x; 1.1021x over previous
//
#include <hip/hip_runtime.h>

// Detect (SSD post-process), FULLY FUSED: one kernel, one block per batch.
// B=128 P=8732 C=21 TOP_K=200 CONF=0.01 NMS=0.45
//
// Phase A: stream conf through LDS tiles, f64 softmax (bit-identical to R4),
//          keys (40-bit f64 score | 14-bit idx-desc | 5-bit cls) -> LDS Ks[].
// Phase B: 12-bit radix select on key bits 54..43 (monotone for score in
//          (0.01,2): exponent in [1016,1023] -> low 3 exp bits monotone) ->
//          ballot compact -> rank sort -> kill-mask matrix -> single uniform
//          resolve -> lane-parallel output. Round loop w/ shrinking ubound.
//
// Equivalence: scan candidates in (score desc, index asc) order, accept iff no
// previously-ACCEPTED same-class box has IoU>0.45, stop at 200; rest zero.
// IoU compare in mul-form (inter > 0.45*denom): margins >> f32 ulp (R2-f32 passed).
//
// d_ws unused.

typedef unsigned long long u64;

#define BATCH 128
#define NPRIOR 8732
#define NCLS 21
#define TOPK 200
#define T 1024
#define TARGET 256
#define CAP 384
#define NBIN 4096
#define KW 6
#define TILE 512

__device__ __forceinline__ double exp_fast(double x) {
  // exp for |x| < ~50, rel err < 1e-14 (bit-identical to R3/R4 decisions)
  const double LOG2E = 1.4426950408889634;
  const double LN2_HI = 6.93147180369123816490e-01;
  const double LN2_LO = 1.90821492927058770002e-10;
  double n = rint(x * LOG2E);
  double r = fma(-n, LN2_HI, x);
  r = fma(-n, LN2_LO, r);
  double p = 2.505210838544172e-08;
  p = fma(p, r, 2.755731922398589e-07);
  p = fma(p, r, 2.7557319223985893e-06);
  p = fma(p, r, 2.48015873015873e-05);
  p = fma(p, r, 1.984126984126984e-04);
  p = fma(p, r, 1.388888888888889e-03);
  p = fma(p, r, 8.333333333333333e-03);
  p = fma(p, r, 4.1666666666666664e-02);
  p = fma(p, r, 1.6666666666666666e-01);
  p = fma(p, r, 0.5);
  p = fma(p, r, 1.0);
  p = fma(p, r, 1.0);
  return ldexp(p, (int)n);
}

// Find descending cutoff bin: cut[0]=c, cut[1]=count in bins>c, cut[2]=count
// in bins>=c (M). wtot[16]=total. tcap caps the target. 3 barriers.
__device__ __forceinline__ void radix_cut(const int* hist, int tid, int tcap,
                                          int* wtot, int* cut) {
  if (tid == 0) cut[2] = 0;
  const int base = tid * 4;
  const int cs = hist[base] + hist[base + 1] + hist[base + 2] + hist[base + 3];
  const int lane = tid & 63;
  int suf = cs;  // within-wave inclusive suffix sum
#pragma unroll
  for (int off = 1; off < 64; off <<= 1) {
    int v = __shfl_down(suf, off);
    if (lane + off < 64) suf += v;
  }
  if (lane == 0) wtot[tid >> 6] = suf;
  __syncthreads();
  if (tid < 16) {  // wave 0: exclusive suffix over following waves
    int v = wtot[tid];
    int s = v;
#pragma unroll
    for (int off = 1; off < 16; off <<= 1) {
      int o = __shfl_down(s, off);
      if (tid + off < 16) s += o;
    }
    if (tid == 0) wtot[16] = s;  // grand total
    wtot[tid] = s - v;
  }
  __syncthreads();
  const int total = wtot[16];
  if (total > 0) {
    const int target = total < tcap ? total : tcap;
    const int S = suf + wtot[tid >> 6];  // inclusive suffix from my chunk
    const int Snext = S - cs;
    if (S >= target && Snext < target) {  // unique crossing thread
      int acc = Snext;
      for (int bn = base + 3; bn >= base; --bn) {
        acc += hist[bn];
        if (acc >= target) {
          cut[0] = bn; cut[1] = acc - hist[bn]; cut[2] = acc;
          break;
        }
      }
    }
  }
  __syncthreads();
}

__global__ __launch_bounds__(T) void detect_fused(
    const float* __restrict__ loc, const float* __restrict__ conf,
    const float* __restrict__ prior, float* __restrict__ out) {
  __shared__ u64 Ks[NPRIOR];                  // 69,856 B (persistent)
  __shared__ __align__(16) char pool[50176];  // phase A stage / phase B carve
  __shared__ int wtot[17];
  __shared__ int cut1[3], cut2[3];
  __shared__ u64 Ash[KW], KFsh[KW], ACCsh[KW];
  __shared__ float4 abox[TOPK];
  __shared__ float aar[TOPK];
  __shared__ int acl[TOPK];
  __shared__ int sh_cnt, sh_nA;
  __shared__ u64 sh_ub;
  // ~125 KB of 160 KB/CU

  const int tid = threadIdx.x;
  const int b = blockIdx.x;
  const float4* loc4 = ((const float4*)loc) + (long long)b * NPRIOR;
  const float4* pr4 = (const float4*)prior;
  float* outb = out + (long long)b * (TOPK * 6);

  if (tid == 0) { sh_nA = 0; sh_ub = ~0ULL; }

  // ---------------- Phase A: softmax -> keys in LDS ----------------
  {
    const float* confb = conf + (long long)b * (NPRIOR * NCLS);
    float* stage = (float*)pool;
    for (int tile = 0; tile < NPRIOR; tile += TILE) {
      const int rows = (NPRIOR - tile < TILE) ? (NPRIOR - tile) : TILE;
      const int nf4 = (rows * NCLS) >> 2;  // rows*21 % 4 == 0 for 512 and 540
      const float4* src = (const float4*)(confb + (long long)tile * NCLS);
      float4* dst = (float4*)stage;
      for (int k = tid; k < nf4; k += T) dst[k] = src[k];
      __syncthreads();
      if (tid < rows) {
        const float* row = stage + tid * NCLS;
        double m = (double)row[0];
#pragma unroll
        for (int j = 1; j < NCLS; ++j) m = fmax(m, (double)row[j]);
        double sum = 0.0, best = -1.0;
        int bi = 1;
#pragma unroll
        for (int j = 0; j < NCLS; ++j) {
          double ej = exp_fast((double)row[j] - m);
          sum += ej;
          if (j >= 1 && ej > best) { best = ej; bi = j; }  // first-idx ties
        }
        double score = best / sum;
        const int p = tile + tid;
        u64 key = 0ULL;
        if (score > 0.01) {
          u64 sb = (u64)__double_as_longlong(score);  // >0: bit order == value order
          key = ((sb >> 24) << 24) | ((u64)(16383 - p) << 10) | (u64)(bi - 1);
        }
        Ks[p] = key;
      }
      __syncthreads();
    }
  }

  // ---------------- Phase B: select + sort + NMS ----------------
  int* hist = (int*)pool;                   // 16,384 B
  u64* buf = (u64*)(pool + 16384);          //  3,072 B
  u64* buf2 = (u64*)(pool + 19456);         //  3,072 B (sorted desc)
  float4* cbox = (float4*)(pool + 22528);   //  6,144 B
  float* car = (float*)(pool + 28672);      //  1,536 B
  int* ccl = (int*)(pool + 30208);          //  1,536 B
  u64* KILL = (u64*)(pool + 31744);         // 18,432 B -> ends 50,176

  while (true) {
    for (int i = tid; i < NBIN; i += T) hist[i] = 0;
    __syncthreads();
    const u64 ub = sh_ub;
    // L1 histogram: key bits 54..43 (monotone; ~3500 spread bins)
    for (int i = tid; i < NPRIOR; i += T) {
      u64 k = Ks[i];
      if (k && k < ub) atomicAdd(&hist[(int)((k >> 43) & 0xFFF)], 1);
    }
    __syncthreads();
    radix_cut(hist, tid, TARGET, wtot, cut1);
    const int total = wtot[16];
    int M = cut1[2];
    if (M == 0) break;  // nothing remains
    const int c1 = cut1[0];
    const int baseA = cut1[1];
    const bool need2 = (M > CAP);
    int c2 = 0;
    if (need2) {  // rare: refine within bin c1 on key bits 42..31
      for (int i = tid; i < NBIN; i += T) hist[i] = 0;
      __syncthreads();
      for (int i = tid; i < NPRIOR; i += T) {
        u64 k = Ks[i];
        if (k && k < ub && (int)((k >> 43) & 0xFFF) == c1)
          atomicAdd(&hist[(int)((k >> 31) & 0xFFF)], 1);
      }
      __syncthreads();
      const int tcap2 = (total < TARGET ? total : TARGET) - baseA;
      radix_cut(hist, tid, tcap2, wtot, cut2);
      c2 = cut2[0];
      M = baseA + cut2[2];
      if (M > CAP) {  // >=129 keys within 2^-21 rel score window: ~impossible
        int Md = M - hist[c2];
        if (Md > 0) { M = Md; c2 = c2 + 1; } else { M = CAP; }  // unreachable
      }
    }
    if (tid == 0) sh_cnt = 0;
    __syncthreads();
    // compact (ballot + 1 atomic/wave); order irrelevant (rank sort next)
    for (int i = tid; i < NPRIOR; i += T) {
      u64 k = Ks[i];
      bool psel = false;
      if (k && k < ub) {
        int b1 = (int)((k >> 43) & 0xFFF);
        psel = need2 ? (b1 > c1 || (b1 == c1 && (int)((k >> 31) & 0xFFF) >= c2))
                     : (b1 >= c1);
      }
      u64 mask = __ballot(psel ? 1 : 0);
      if (mask) {
        int lane = tid & 63;
        int leader = __ffsll((unsigned long long)mask) - 1;
        int bpos = 0;
        if (lane == leader) bpos = atomicAdd(&sh_cnt, __popcll(mask));
        bpos = __shfl(bpos, leader);
        if (psel) {
          int pos = bpos + __popcll(mask & ((1ULL << lane) - 1ULL));
          if (pos < CAP) buf[pos] = k;
        }
      }
    }
    __syncthreads();
    int Mr = sh_cnt;
    if (Mr > CAP) Mr = CAP;
    if (Mr == 0) break;  // defensive
    // rank sort (keys unique): buf2[rank] = key, descending
    {
      u64 ka = (tid < Mr) ? buf[tid] : 0ULL;
      int ra = 0;
      if (tid < Mr)
        for (int i = 0; i < Mr; ++i) ra += (buf[i] > ka);  // LDS broadcast
      if (tid < Mr) buf2[ra] = ka;
    }
    if (tid < KW) { Ash[tid] = 0ULL; KFsh[tid] = 0ULL; }
    __syncthreads();
    const int nA0 = sh_nA;
    // decode candidates on demand (bit-identical f64 ops)
    if (tid < Mr) {
      const int t = tid;
      u64 k = buf2[t];
      int cl = (int)(k & 0x1FULL);
      int p = 16383 - (int)((k >> 10) & 0x3FFFULL);
      float4 l = loc4[p];
      float4 pr = pr4[p];
      double cx = (double)pr.x + (double)l.x * 0.1 * (double)pr.z;
      double cy = (double)pr.y + (double)l.y * 0.1 * (double)pr.w;
      double w = (double)pr.z * exp_fast((double)l.z * 0.2);
      double h = (double)pr.w * exp_fast((double)l.w * 0.2);
      float x1 = (float)(cx - w * 0.5), y1 = (float)(cy - h * 0.5);
      float x2 = (float)(cx + w * 0.5), y2 = (float)(cy + h * 0.5);
      cbox[t] = make_float4(x1, y1, x2, y2);
      car[t] = (x2 - x1) * (y2 - y1);
      ccl[t] = cl;
    }
    __syncthreads();
    // pre-round suppression vs already-accepted (rounds >= 2 only)
    if (nA0 > 0 && tid < Mr) {
      const int t = tid;
      float4 my = cbox[t];
      float mar = car[t];
      int mcl = ccl[t];
      bool sup = false;
      for (int a = 0; a < nA0; ++a) {
        if (acl[a] == mcl) {
          float4 ab = abox[a];
          float ix1 = fmaxf(ab.x, my.x), iy1 = fmaxf(ab.y, my.y);
          float ix2 = fminf(ab.z, my.z), iy2 = fminf(ab.w, my.w);
          float inter = fmaxf(ix2 - ix1, 0.f) * fmaxf(iy2 - iy1, 0.f);
          if (inter > 0.45f * (aar[a] + mar - inter)) sup = true;
        }
      }
      if (sup) atomicOr(&Ash[t >> 6], 1ULL << (t & 63));
    }
    // kill-mask matrix over (candidate t, 64-wide segment seg): wave-uniform
    // seg (512 % 64 == 0) keeps inner cbox[i] reads broadcast.
    for (int idx = tid; idx < KW * 512; idx += T) {
      const int seg = idx >> 9;
      const int t = idx & 511;
      if (t < Mr) {
        const int i0 = seg * 64;
        int i1 = i0 + 64;
        if (i1 > Mr) i1 = Mr;
        u64 mm = 0ULL;
        if (i1 > t) {  // only later candidates can be killed
          float4 my = cbox[t];
          float mar = car[t];
          int mcl = ccl[t];
          int is = (i0 > t + 1) ? i0 : (t + 1);
          for (int i = is; i < i1; ++i) {
            if (ccl[i] == mcl) {
              float4 cb = cbox[i];
              float ix1 = fmaxf(my.x, cb.x), iy1 = fmaxf(my.y, cb.y);
              float ix2 = fminf(my.z, cb.z), iy2 = fminf(my.w, cb.w);
              float inter = fmaxf(ix2 - ix1, 0.f) * fmaxf(iy2 - iy1, 0.f);
              if (inter > 0.45f * (mar + car[i] - inter))
                mm |= 1ULL << (i - i0);
            }
          }
        }
        KILL[t * KW + seg] = mm;
        if (mm) atomicOr(&KFsh[t >> 6], 1ULL << (t & 63));
      }
    }
    __syncthreads();
    // uniform serial resolve on wave 0 (registers; LDS row load only on kill)
    if (tid < 64) {
      u64 A0, A1, A2, A3, A4, A5;
      {
        u64 v[KW];
#pragma unroll
        for (int w = 0; w < KW; ++w) {
          int rem = Mr - 64 * w;
          u64 vm = (rem >= 64) ? ~0ULL : (rem <= 0 ? 0ULL : ((1ULL << rem) - 1ULL));
          v[w] = vm & ~Ash[w];
        }
        A0 = v[0]; A1 = v[1]; A2 = v[2]; A3 = v[3]; A4 = v[4]; A5 = v[5];
      }
      u64 C0 = 0, C1 = 0, C2 = 0, C3 = 0, C4 = 0, C5 = 0;
      int nacc = nA0;
      bool full = false;
#define KILLUPD(cidx) do { const u64* kc = &KILL[(cidx) * KW];      \
      A0 &= ~kc[0]; A1 &= ~kc[1]; A2 &= ~kc[2];                     \
      A3 &= ~kc[3]; A4 &= ~kc[4]; A5 &= ~kc[5]; } while (0)
#define RESW(w, Aw, Cw) if (!full) {                                \
      const u64 KFw = KFsh[w];                                      \
      int lim = Mr - (w) * 64; if (lim > 64) lim = 64;              \
      for (int q = 0; q < lim; ++q) {                               \
        if ((Aw >> q) & 1ULL) {                                     \
          Cw |= 1ULL << q; ++nacc;                                  \
          if (nacc == TOPK) { full = true; break; }                 \
          if ((KFw >> q) & 1ULL) KILLUPD((w) * 64 + q);             \
        } } }
      RESW(0, A0, C0)
      RESW(1, A1, C1)
      RESW(2, A2, C2)
      RESW(3, A3, C3)
      RESW(4, A4, C4)
      RESW(5, A5, C5)
#undef RESW
#undef KILLUPD
      if (tid == 0) {
        ACCsh[0] = C0; ACCsh[1] = C1; ACCsh[2] = C2;
        ACCsh[3] = C3; ACCsh[4] = C4; ACCsh[5] = C5;
        sh_nA = nacc;
        sh_ub = buf2[Mr - 1];  // all unselected keys are strictly below
      }
    }
    __syncthreads();
    // lane-parallel output of accepted candidates
    if (tid < Mr) {
      const int t = tid;
      const int w = t >> 6, q = t & 63;
      const u64 accw = ACCsh[w];
      if ((accw >> q) & 1ULL) {
        int rank = nA0;
#pragma unroll
        for (int w2 = 0; w2 < KW; ++w2)
          if (w2 < w) rank += __popcll(ACCsh[w2]);
        rank += __popcll(accw & ((q == 0) ? 0ULL : ((1ULL << q) - 1ULL)));
        float4 bx = cbox[t];
        float sc = (float)__longlong_as_double((long long)((buf2[t] >> 24) << 24));
        float* o = outb + rank * 6;
        o[0] = bx.x; o[1] = bx.y; o[2] = bx.z; o[3] = bx.w;
        o[4] = sc; o[5] = (float)ccl[t];
        abox[rank] = bx; aar[rank] = car[t]; acl[rank] = ccl[t];
      }
    }
    __syncthreads();
    if (sh_nA >= TOPK) break;
    if (total - Mr <= 0) break;  // pool exhausted
  }
  // zero-fill rows [nA, TOPK)
  const int nAf = sh_nA;
  for (int i = nAf * 6 + tid; i < TOPK * 6; i += T) outb[i] = 0.0f;
}

extern "C" void kernel_launch(void* const* d_in, const int* in_sizes, int n_in,
                              void* d_out, int out_size, void* d_ws,
                              size_t ws_size, hipStream_t stream) {
  const float* loc = (const float*)d_in[0];    // B*P*4
  const float* conf = (const float*)d_in[1];   // B*P*21
  const float* prior = (const float*)d_in[2];  // P*4
  float* out = (float*)d_out;                  // B*200*6
  detect_fused<<<BATCH, T, 0, stream>>>(loc, conf, prior, out);
}

// Round 6
// 223.522 us; speedup vs baseline: 11.0298x; 1.1034x over previous
//
#include <hip/hip_runtime.h>

// Detect (SSD post-process), fully fused: one kernel, one block per batch.
// B=128 P=8732 C=21 TOP_K=200 CONF=0.01 NMS=0.45
//
// Phase A: stream conf through 1024-row LDS tiles; APPROX f32 softmax score
//          (HW v_exp_f32) -> selection keys (f32 bits | idx-desc | cls) in LDS.
// Phase B: monotone 12-bit radix select (key bits 57..46; scores in (0.01,2)
//          have constant top 6 bits) -> ballot compact -> EXACT f64 rescore of
//          the <=384 selected rows (bit-identical to R5's validated pipeline)
//          -> rank sort on exact keys -> kill-mask matrix -> uniform resolve
//          -> lane-parallel output. Round loop w/ approx-pivot ubound.
//
// Selection-set safety: approx error ~1e-6 rel vs top-220/top-256 score gap
// ~3e-2; 0.01-threshold rows sit at rank ~8000 (never emitted). All decisions
// on emitted rows use the exact f64 scores -> identical to R5 (passed).
//
// d_ws unused.

typedef unsigned long long u64;

#define BATCH 128
#define NPRIOR 8732
#define NCLS 21
#define TOPK 200
#define T 1024
#define TARGET 256
#define CAP 384
#define NBIN 4096
#define KW 6
#define TILE 1024

__device__ __forceinline__ double exp_fast(double x) {
  // exp for |x| < ~50, rel err < 1e-14 (bit-identical to R3/R4/R5 decisions)
  const double LOG2E = 1.4426950408889634;
  const double LN2_HI = 6.93147180369123816490e-01;
  const double LN2_LO = 1.90821492927058770002e-10;
  double n = rint(x * LOG2E);
  double r = fma(-n, LN2_HI, x);
  r = fma(-n, LN2_LO, r);
  double p = 2.505210838544172e-08;
  p = fma(p, r, 2.755731922398589e-07);
  p = fma(p, r, 2.7557319223985893e-06);
  p = fma(p, r, 2.48015873015873e-05);
  p = fma(p, r, 1.984126984126984e-04);
  p = fma(p, r, 1.388888888888889e-03);
  p = fma(p, r, 8.333333333333333e-03);
  p = fma(p, r, 4.1666666666666664e-02);
  p = fma(p, r, 1.6666666666666666e-01);
  p = fma(p, r, 0.5);
  p = fma(p, r, 1.0);
  p = fma(p, r, 1.0);
  return ldexp(p, (int)n);
}

// Descending cutoff bin over hist[4096]: cut[0]=c, cut[1]=count in bins>c,
// cut[2]=count in bins>=c. wtot[16]=grand total. 3 barriers.
__device__ __forceinline__ void radix_cut(const int* hist, int tid, int tcap,
                                          int* wtot, int* cut) {
  if (tid == 0) cut[2] = 0;
  const int base = tid * 4;
  const int cs = hist[base] + hist[base + 1] + hist[base + 2] + hist[base + 3];
  const int lane = tid & 63;
  int suf = cs;  // within-wave inclusive suffix sum
#pragma unroll
  for (int off = 1; off < 64; off <<= 1) {
    int v = __shfl_down(suf, off);
    if (lane + off < 64) suf += v;
  }
  if (lane == 0) wtot[tid >> 6] = suf;
  __syncthreads();
  if (tid < 16) {  // wave 0: exclusive suffix over following waves
    int v = wtot[tid];
    int s = v;
#pragma unroll
    for (int off = 1; off < 16; off <<= 1) {
      int o = __shfl_down(s, off);
      if (tid + off < 16) s += o;
    }
    if (tid == 0) wtot[16] = s;  // grand total
    wtot[tid] = s - v;
  }
  __syncthreads();
  const int total = wtot[16];
  if (total > 0) {
    const int target = total < tcap ? total : tcap;
    const int S = suf + wtot[tid >> 6];
    const int Snext = S - cs;
    if (S >= target && Snext < target) {  // unique crossing thread
      int acc = Snext;
      for (int bn = base + 3; bn >= base; --bn) {
        acc += hist[bn];
        if (acc >= target) {
          cut[0] = bn; cut[1] = acc - hist[bn]; cut[2] = acc;
          break;
        }
      }
    }
  }
  __syncthreads();
}

__global__ __launch_bounds__(T) void detect_fused(
    const float* __restrict__ loc, const float* __restrict__ conf,
    const float* __restrict__ prior, float* __restrict__ out) {
  __shared__ u64 Ks[NPRIOR];                  // 69,856 B (persistent approx keys)
  __shared__ __align__(16) char pool[86016];  // A: 1024-row stage / B: carve
  __shared__ int wtot[17];
  __shared__ int cut1[3], cut2[3];
  __shared__ u64 Ash[KW], KFsh[KW], ACCsh[KW];
  __shared__ float4 abox[TOPK];
  __shared__ float aar[TOPK];
  __shared__ int acl[TOPK];
  __shared__ int sh_cnt, sh_nA;
  __shared__ u64 sh_ub;
  // ~161 KB of 160 KiB/CU -> 1 block/CU

  const int tid = threadIdx.x;
  const int b = blockIdx.x;
  const float* confb = conf + (long long)b * (NPRIOR * NCLS);
  const float4* loc4 = ((const float4*)loc) + (long long)b * NPRIOR;
  const float4* pr4 = (const float4*)prior;
  float* outb = out + (long long)b * (TOPK * 6);

  if (tid == 0) { sh_nA = 0; sh_ub = ~0ULL; }

  // ---------- Phase A: approx f32 softmax -> selection keys in LDS ----------
  {
    float* stage = (float*)pool;
    for (int tile = 0; tile < NPRIOR; tile += TILE) {
      const int rows = (NPRIOR - tile < TILE) ? (NPRIOR - tile) : TILE;
      const int nf4 = (rows * NCLS) >> 2;  // 1024*21/4=5376, 540*21/4=2835
      const float4* src = (const float4*)(confb + (long long)tile * NCLS);
      float4* dst = (float4*)stage;
      for (int k = tid; k < nf4; k += T) dst[k] = src[k];
      __syncthreads();
      if (tid < rows) {
        const float* row = stage + tid * NCLS;
        float m = row[0];
#pragma unroll
        for (int j = 1; j < NCLS; ++j) m = fmaxf(m, row[j]);
        float sum = __expf(row[0] - m);
        float bestr = row[1];
        float beste = __expf(row[1] - m);
        sum += beste;
        int bi = 1;
#pragma unroll
        for (int j = 2; j < NCLS; ++j) {
          float rv = row[j];
          float ej = __expf(rv - m);
          sum += ej;
          if (rv > bestr) { bestr = rv; bi = j; beste = ej; }  // first-idx ties
        }
        float score = __fdividef(beste, sum);  // approx ok: selection only
        const int p = tile + tid;
        u64 key = 0ULL;
        if (score > 0.01f) {
          // f32 bits | idx-desc | cls. Scores in (0.01,2): u64 bits 63..58
          // constant -> bits 57..46 are a monotone 12-bit bin.
          key = ((u64)__float_as_uint(score) << 32) |
                ((u64)(16383 - p) << 10) | (u64)(bi - 1);
        }
        Ks[p] = key;
      }
      __syncthreads();
    }
  }

  // ---------- Phase B: select + exact rescore + sort + NMS ----------
  int* hist = (int*)pool;                   // 16,384 B
  u64* buf = (u64*)(pool + 16384);          //  3,072 B (approx, unordered)
  u64* ebuf = (u64*)(pool + 19456);         //  3,072 B (exact keys)
  u64* buf2 = (u64*)(pool + 22528);         //  3,072 B (exact, sorted desc)
  float4* cbox = (float4*)(pool + 25600);   //  6,144 B
  float* car = (float*)(pool + 31744);      //  1,536 B
  int* ccl = (int*)(pool + 33280);          //  1,536 B
  u64* KILL = (u64*)(pool + 34816);         // 18,432 B -> ends 53,248

  while (true) {
    for (int i = tid; i < NBIN; i += T) hist[i] = 0;
    __syncthreads();
    const u64 ub = sh_ub;
    // L1 histogram: approx-key bits 57..46 (monotone, ~2000 spread bins)
    for (int i = tid; i < NPRIOR; i += T) {
      u64 k = Ks[i];
      if (k && k < ub) atomicAdd(&hist[(int)((k >> 46) & 0xFFF)], 1);
    }
    __syncthreads();
    radix_cut(hist, tid, TARGET, wtot, cut1);
    const int total = wtot[16];
    int M = cut1[2];
    if (M == 0) break;  // nothing remains
    const int c1 = cut1[0];
    const int baseA = cut1[1];
    const bool need2 = (M > CAP);
    int c2 = 0;
    if (need2) {  // rare: refine within bin c1 on bits 45..34
      for (int i = tid; i < NBIN; i += T) hist[i] = 0;
      __syncthreads();
      for (int i = tid; i < NPRIOR; i += T) {
        u64 k = Ks[i];
        if (k && k < ub && (int)((k >> 46) & 0xFFF) == c1)
          atomicAdd(&hist[(int)((k >> 34) & 0xFFF)], 1);
      }
      __syncthreads();
      const int tcap2 = (total < TARGET ? total : TARGET) - baseA;
      radix_cut(hist, tid, tcap2, wtot, cut2);
      c2 = cut2[0];
      M = baseA + cut2[2];
      if (M > CAP) {  // >=129 keys in one 2^-11 rel f32 window: ~impossible
        int Md = M - hist[c2];
        if (Md > 0) { M = Md; c2 = c2 + 1; } else { M = CAP; }
      }
    }
    if (tid == 0) {
      sh_cnt = 0;
      // next-round ubound = monotone pivot (selected set == {k >= pivot})
      sh_ub = need2 ? (((u64)c1 << 46) + ((u64)c2 << 34)) : ((u64)c1 << 46);
    }
    __syncthreads();
    // compact (ballot + 1 atomic/wave); order irrelevant (rank sort later)
    for (int i = tid; i < NPRIOR; i += T) {
      u64 k = Ks[i];
      bool psel = false;
      if (k && k < ub) {
        int b1 = (int)((k >> 46) & 0xFFF);
        psel = need2 ? (b1 > c1 || (b1 == c1 && (int)((k >> 34) & 0xFFF) >= c2))
                     : (b1 >= c1);
      }
      u64 mask = __ballot(psel ? 1 : 0);
      if (mask) {
        int lane = tid & 63;
        int leader = __ffsll((unsigned long long)mask) - 1;
        int bpos = 0;
        if (lane == leader) bpos = atomicAdd(&sh_cnt, __popcll(mask));
        bpos = __shfl(bpos, leader);
        if (psel) {
          int pos = bpos + __popcll(mask & ((1ULL << lane) - 1ULL));
          if (pos < CAP) buf[pos] = k;
        }
      }
    }
    __syncthreads();
    int Mr = sh_cnt;
    if (Mr > CAP) Mr = CAP;
    if (Mr == 0) break;  // defensive
    // EXACT f64 rescore of selected rows (bit-identical to R5's pipeline)
    if (tid < Mr) {
      u64 ak = buf[tid];
      int cl = (int)(ak & 0x1FULL);
      int p = 16383 - (int)((ak >> 10) & 0x3FFFULL);
      const float* crow = confb + (long long)p * NCLS;
      double m = (double)crow[0];
#pragma unroll
      for (int j = 1; j < NCLS; ++j) m = fmax(m, (double)crow[j]);
      double sum = 0.0, best = -1.0;
#pragma unroll
      for (int j = 0; j < NCLS; ++j) {
        double ej = exp_fast((double)crow[j] - m);
        sum += ej;
        if (j >= 1 && ej > best) best = ej;  // value only; cl fixed by argmax
      }
      double score = best / sum;
      u64 sb = (u64)__double_as_longlong(score);
      ebuf[tid] = ((sb >> 24) << 24) | ((u64)(16383 - p) << 10) | (u64)cl;
    }
    __syncthreads();
    // rank sort on exact keys (unique): buf2[rank] = ekey, descending
    if (tid < Mr) {
      u64 ka = ebuf[tid];
      int ra = 0;
      for (int i = 0; i < Mr; ++i) ra += (ebuf[i] > ka);  // LDS broadcast
      buf2[ra] = ka;
    }
    if (tid < KW) { Ash[tid] = 0ULL; KFsh[tid] = 0ULL; }
    __syncthreads();
    const int nA0 = sh_nA;
    // decode candidates on demand (bit-identical f64 ops)
    if (tid < Mr) {
      const int t = tid;
      u64 k = buf2[t];
      int cl = (int)(k & 0x1FULL);
      int p = 16383 - (int)((k >> 10) & 0x3FFFULL);
      float4 l = loc4[p];
      float4 pr = pr4[p];
      double cx = (double)pr.x + (double)l.x * 0.1 * (double)pr.z;
      double cy = (double)pr.y + (double)l.y * 0.1 * (double)pr.w;
      double w = (double)pr.z * exp_fast((double)l.z * 0.2);
      double h = (double)pr.w * exp_fast((double)l.w * 0.2);
      float x1 = (float)(cx - w * 0.5), y1 = (float)(cy - h * 0.5);
      float x2 = (float)(cx + w * 0.5), y2 = (float)(cy + h * 0.5);
      cbox[t] = make_float4(x1, y1, x2, y2);
      car[t] = (x2 - x1) * (y2 - y1);
      ccl[t] = cl;
    }
    __syncthreads();
    // pre-round suppression vs already-accepted (rounds >= 2 only)
    if (nA0 > 0 && tid < Mr) {
      const int t = tid;
      float4 my = cbox[t];
      float mar = car[t];
      int mcl = ccl[t];
      bool sup = false;
      for (int a = 0; a < nA0; ++a) {
        if (acl[a] == mcl) {
          float4 ab = abox[a];
          float ix1 = fmaxf(ab.x, my.x), iy1 = fmaxf(ab.y, my.y);
          float ix2 = fminf(ab.z, my.z), iy2 = fminf(ab.w, my.w);
          float inter = fmaxf(ix2 - ix1, 0.f) * fmaxf(iy2 - iy1, 0.f);
          if (inter > 0.45f * (aar[a] + mar - inter)) sup = true;
        }
      }
      if (sup) atomicOr(&Ash[t >> 6], 1ULL << (t & 63));
    }
    // kill-mask matrix over (candidate t, 64-wide segment): wave-uniform seg
    for (int idx = tid; idx < KW * 512; idx += T) {
      const int seg = idx >> 9;
      const int t = idx & 511;
      if (t < Mr) {
        const int i0 = seg * 64;
        int i1 = i0 + 64;
        if (i1 > Mr) i1 = Mr;
        u64 mm = 0ULL;
        if (i1 > t) {
          float4 my = cbox[t];
          float mar = car[t];
          int mcl = ccl[t];
          int is = (i0 > t + 1) ? i0 : (t + 1);
          for (int i = is; i < i1; ++i) {
            if (ccl[i] == mcl) {
              float4 cb = cbox[i];
              float ix1 = fmaxf(my.x, cb.x), iy1 = fmaxf(my.y, cb.y);
              float ix2 = fminf(my.z, cb.z), iy2 = fminf(my.w, cb.w);
              float inter = fmaxf(ix2 - ix1, 0.f) * fmaxf(iy2 - iy1, 0.f);
              if (inter > 0.45f * (mar + car[i] - inter))
                mm |= 1ULL << (i - i0);
            }
          }
        }
        KILL[t * KW + seg] = mm;
        if (mm) atomicOr(&KFsh[t >> 6], 1ULL << (t & 63));
      }
    }
    __syncthreads();
    // uniform serial resolve on wave 0 (registers; LDS row load only on kill)
    if (tid < 64) {
      u64 A0, A1, A2, A3, A4, A5;
      {
        u64 v[KW];
#pragma unroll
        for (int w = 0; w < KW; ++w) {
          int rem = Mr - 64 * w;
          u64 vm = (rem >= 64) ? ~0ULL : (rem <= 0 ? 0ULL : ((1ULL << rem) - 1ULL));
          v[w] = vm & ~Ash[w];
        }
        A0 = v[0]; A1 = v[1]; A2 = v[2]; A3 = v[3]; A4 = v[4]; A5 = v[5];
      }
      u64 C0 = 0, C1 = 0, C2 = 0, C3 = 0, C4 = 0, C5 = 0;
      int nacc = nA0;
      bool full = false;
#define KILLUPD(cidx) do { const u64* kc = &KILL[(cidx) * KW];      \
      A0 &= ~kc[0]; A1 &= ~kc[1]; A2 &= ~kc[2];                     \
      A3 &= ~kc[3]; A4 &= ~kc[4]; A5 &= ~kc[5]; } while (0)
#define RESW(w, Aw, Cw) if (!full) {                                \
      const u64 KFw = KFsh[w];                                      \
      int lim = Mr - (w) * 64; if (lim > 64) lim = 64;              \
      for (int q = 0; q < lim; ++q) {                               \
        if ((Aw >> q) & 1ULL) {                                     \
          Cw |= 1ULL << q; ++nacc;                                  \
          if (nacc == TOPK) { full = true; break; }                 \
          if ((KFw >> q) & 1ULL) KILLUPD((w) * 64 + q);             \
        } } }
      RESW(0, A0, C0)
      RESW(1, A1, C1)
      RESW(2, A2, C2)
      RESW(3, A3, C3)
      RESW(4, A4, C4)
      RESW(5, A5, C5)
#undef RESW
#undef KILLUPD
      if (tid == 0) {
        ACCsh[0] = C0; ACCsh[1] = C1; ACCsh[2] = C2;
        ACCsh[3] = C3; ACCsh[4] = C4; ACCsh[5] = C5;
        sh_nA = nacc;
      }
    }
    __syncthreads();
    // lane-parallel output of accepted candidates
    if (tid < Mr) {
      const int t = tid;
      const int w = t >> 6, q = t & 63;
      const u64 accw = ACCsh[w];
      if ((accw >> q) & 1ULL) {
        int rank = nA0;
#pragma unroll
        for (int w2 = 0; w2 < KW; ++w2)
          if (w2 < w) rank += __popcll(ACCsh[w2]);
        rank += __popcll(accw & ((q == 0) ? 0ULL : ((1ULL << q) - 1ULL)));
        float4 bx = cbox[t];
        float sc = (float)__longlong_as_double((long long)((buf2[t] >> 24) << 24));
        float* o = outb + rank * 6;
        o[0] = bx.x; o[1] = bx.y; o[2] = bx.z; o[3] = bx.w;
        o[4] = sc; o[5] = (float)ccl[t];
        abox[rank] = bx; aar[rank] = car[t]; acl[rank] = ccl[t];
      }
    }
    __syncthreads();
    if (sh_nA >= TOPK) break;
    if (total - Mr <= 0) break;  // pool exhausted
  }
  // zero-fill rows [nA, TOPK)
  const int nAf = sh_nA;
  for (int i = nAf * 6 + tid; i < TOPK * 6; i += T) outb[i] = 0.0f;
}

extern "C" void kernel_launch(void* const* d_in, const int* in_sizes, int n_in,
                              void* d_out, int out_size, void* d_ws,
                              size_t ws_size, hipStream_t stream) {
  const float* loc = (const float*)d_in[0];    // B*P*4
  const float* conf = (const float*)d_in[1];   // B*P*21
  const float* prior = (const float*)d_in[2];  // P*4
  float* out = (float*)d_out;                  // B*200*6
  detect_fused<<<BATCH, T, 0, stream>>>(loc, conf, prior, out);
}

// Round 7
// 211.177 us; speedup vs baseline: 11.6745x; 1.0585x over previous
//
#include <hip/hip_runtime.h>

// Detect (SSD post-process). B=128 P=8732 C=21 TOP_K=200 CONF=0.01 NMS=0.45
//
// R7 split: the conf stream (94 MB) must run on ALL 256 CUs with deep MLP ->
// separate prep kernel (4366 blocks); per-batch NMS stays 128 blocks.
//
// prep: stage 256 conf rows/block via float4 -> approx f32 softmax score
//       (HW v_exp_f32; R6-validated selection accuracy) -> key u64
//       (f32 score bits | 14-bit idx-desc | 5-bit cls) -> global ws.
// nms:  R6's validated phase B: monotone 12-bit radix select (bits 57..46) ->
//       ballot compact -> EXACT f64 rescore of <=384 selected rows
//       (bit-identical to R5/R6) -> rank sort -> kill-mask matrix ->
//       uniform resolve -> lane-parallel output. Round loop for correctness.
//
// ws: keys u64[B*P] = 8,941,568 B

typedef unsigned long long u64;

#define BATCH 128
#define NPRIOR 8732
#define NCLS 21
#define TOPK 200
#define T 1024
#define TARGET 256
#define CAP 384
#define NBIN 4096
#define KW 6

__device__ __forceinline__ double exp_fast(double x) {
  // exp for |x| < ~50, rel err < 1e-14 (bit-identical to R3..R6 decisions)
  const double LOG2E = 1.4426950408889634;
  const double LN2_HI = 6.93147180369123816490e-01;
  const double LN2_LO = 1.90821492927058770002e-10;
  double n = rint(x * LOG2E);
  double r = fma(-n, LN2_HI, x);
  r = fma(-n, LN2_LO, r);
  double p = 2.505210838544172e-08;
  p = fma(p, r, 2.755731922398589e-07);
  p = fma(p, r, 2.7557319223985893e-06);
  p = fma(p, r, 2.48015873015873e-05);
  p = fma(p, r, 1.984126984126984e-04);
  p = fma(p, r, 1.388888888888889e-03);
  p = fma(p, r, 8.333333333333333e-03);
  p = fma(p, r, 4.1666666666666664e-02);
  p = fma(p, r, 1.6666666666666666e-01);
  p = fma(p, r, 0.5);
  p = fma(p, r, 1.0);
  p = fma(p, r, 1.0);
  return ldexp(p, (int)n);
}

__global__ __launch_bounds__(256) void prep_kernel(
    const float* __restrict__ conf, u64* __restrict__ keys) {
  __shared__ __align__(16) float srow[256 * NCLS];  // 21504 B
  const int tid = threadIdx.x;
  const long long R0 = (long long)blockIdx.x * 256;
  const float4* src = (const float4*)(conf + R0 * NCLS);
  float4* dst = (float4*)srow;
  for (int k = tid; k < 1344; k += 256) dst[k] = src[k];
  __syncthreads();

  const float* row = srow + tid * NCLS;
  float m = row[0];
#pragma unroll
  for (int j = 1; j < NCLS; ++j) m = fmaxf(m, row[j]);
  float sum = __expf(row[0] - m);
  float bestr = row[1];
  float beste = __expf(row[1] - m);
  sum += beste;
  int bi = 1;
#pragma unroll
  for (int j = 2; j < NCLS; ++j) {
    float rv = row[j];
    float ej = __expf(rv - m);
    sum += ej;
    if (rv > bestr) { bestr = rv; bi = j; beste = ej; }  // first-idx ties
  }
  float score = __fdividef(beste, sum);  // approx ok: selection only

  const long long r = R0 + tid;
  const int p = (int)(r % NPRIOR);
  u64 key = 0ULL;
  if (score > 0.01f) {
    // f32 bits | idx-desc | cls. Scores in (0.01,2): u64 bits 63..58 constant
    // -> bits 57..46 form a monotone 12-bit bin.
    key = ((u64)__float_as_uint(score) << 32) |
          ((u64)(16383 - p) << 10) | (u64)(bi - 1);
  }
  keys[r] = key;
}

// Descending cutoff bin over hist[4096]: cut[0]=c, cut[1]=count in bins>c,
// cut[2]=count in bins>=c. wtot[16]=grand total. 3 barriers.
__device__ __forceinline__ void radix_cut(const int* hist, int tid, int tcap,
                                          int* wtot, int* cut) {
  if (tid == 0) cut[2] = 0;
  const int base = tid * 4;
  const int cs = hist[base] + hist[base + 1] + hist[base + 2] + hist[base + 3];
  const int lane = tid & 63;
  int suf = cs;  // within-wave inclusive suffix sum
#pragma unroll
  for (int off = 1; off < 64; off <<= 1) {
    int v = __shfl_down(suf, off);
    if (lane + off < 64) suf += v;
  }
  if (lane == 0) wtot[tid >> 6] = suf;
  __syncthreads();
  if (tid < 16) {  // wave 0: exclusive suffix over following waves
    int v = wtot[tid];
    int s = v;
#pragma unroll
    for (int off = 1; off < 16; off <<= 1) {
      int o = __shfl_down(s, off);
      if (tid + off < 16) s += o;
    }
    if (tid == 0) wtot[16] = s;  // grand total
    wtot[tid] = s - v;
  }
  __syncthreads();
  const int total = wtot[16];
  if (total > 0) {
    const int target = total < tcap ? total : tcap;
    const int S = suf + wtot[tid >> 6];
    const int Snext = S - cs;
    if (S >= target && Snext < target) {  // unique crossing thread
      int acc = Snext;
      for (int bn = base + 3; bn >= base; --bn) {
        acc += hist[bn];
        if (acc >= target) {
          cut[0] = bn; cut[1] = acc - hist[bn]; cut[2] = acc;
          break;
        }
      }
    }
  }
  __syncthreads();
}

__global__ __launch_bounds__(T) void nms_kernel(
    const float* __restrict__ loc, const float* __restrict__ conf,
    const float* __restrict__ prior, const u64* __restrict__ keys,
    float* __restrict__ out) {
  __shared__ u64 Ks[NPRIOR];                  // 69,856 B
  __shared__ __align__(16) char pool[53248];  // phase-B carve
  __shared__ int wtot[17];
  __shared__ int cut1[3], cut2[3];
  __shared__ u64 Ash[KW], KFsh[KW], ACCsh[KW];
  __shared__ float4 abox[TOPK];
  __shared__ float aar[TOPK];
  __shared__ int acl[TOPK];
  __shared__ int sh_cnt, sh_nA;
  __shared__ u64 sh_ub;
  // ~133 KB -> 1 block/CU (128 blocks; batch-parallel)

  const int tid = threadIdx.x;
  const int b = blockIdx.x;
  const float* confb = conf + (long long)b * (NPRIOR * NCLS);
  const float4* loc4 = ((const float4*)loc) + (long long)b * NPRIOR;
  const float4* pr4 = (const float4*)prior;
  float* outb = out + (long long)b * (TOPK * 6);

  for (int i = tid; i < NPRIOR; i += T) Ks[i] = keys[(long long)b * NPRIOR + i];
  if (tid == 0) { sh_nA = 0; sh_ub = ~0ULL; }
  __syncthreads();

  int* hist = (int*)pool;                   // 16,384 B
  u64* buf = (u64*)(pool + 16384);          //  3,072 B (approx, unordered)
  u64* ebuf = (u64*)(pool + 19456);         //  3,072 B (exact keys)
  u64* buf2 = (u64*)(pool + 22528);         //  3,072 B (exact, sorted desc)
  float4* cbox = (float4*)(pool + 25600);   //  6,144 B
  float* car = (float*)(pool + 31744);      //  1,536 B
  int* ccl = (int*)(pool + 33280);          //  1,536 B
  u64* KILL = (u64*)(pool + 34816);         // 18,432 B -> ends 53,248

  while (true) {
    for (int i = tid; i < NBIN; i += T) hist[i] = 0;
    __syncthreads();
    const u64 ub = sh_ub;
    // L1 histogram: approx-key bits 57..46 (monotone, ~2000 spread bins)
    for (int i = tid; i < NPRIOR; i += T) {
      u64 k = Ks[i];
      if (k && k < ub) atomicAdd(&hist[(int)((k >> 46) & 0xFFF)], 1);
    }
    __syncthreads();
    radix_cut(hist, tid, TARGET, wtot, cut1);
    const int total = wtot[16];
    int M = cut1[2];
    if (M == 0) break;  // nothing remains
    const int c1 = cut1[0];
    const int baseA = cut1[1];
    const bool need2 = (M > CAP);
    int c2 = 0;
    if (need2) {  // rare: refine within bin c1 on bits 45..34
      for (int i = tid; i < NBIN; i += T) hist[i] = 0;
      __syncthreads();
      for (int i = tid; i < NPRIOR; i += T) {
        u64 k = Ks[i];
        if (k && k < ub && (int)((k >> 46) & 0xFFF) == c1)
          atomicAdd(&hist[(int)((k >> 34) & 0xFFF)], 1);
      }
      __syncthreads();
      const int tcap2 = (total < TARGET ? total : TARGET) - baseA;
      radix_cut(hist, tid, tcap2, wtot, cut2);
      c2 = cut2[0];
      M = baseA + cut2[2];
      if (M > CAP) {  // >=129 keys in one 2^-11 rel f32 window: ~impossible
        int Md = M - hist[c2];
        if (Md > 0) { M = Md; c2 = c2 + 1; } else { M = CAP; }
      }
    }
    if (tid == 0) {
      sh_cnt = 0;
      // next-round ubound = monotone pivot (selected set == {k >= pivot})
      sh_ub = need2 ? (((u64)c1 << 46) + ((u64)c2 << 34)) : ((u64)c1 << 46);
    }
    __syncthreads();
    // compact (ballot + 1 atomic/wave); order irrelevant (rank sort later)
    for (int i = tid; i < NPRIOR; i += T) {
      u64 k = Ks[i];
      bool psel = false;
      if (k && k < ub) {
        int b1 = (int)((k >> 46) & 0xFFF);
        psel = need2 ? (b1 > c1 || (b1 == c1 && (int)((k >> 34) & 0xFFF) >= c2))
                     : (b1 >= c1);
      }
      u64 mask = __ballot(psel ? 1 : 0);
      if (mask) {
        int lane = tid & 63;
        int leader = __ffsll((unsigned long long)mask) - 1;
        int bpos = 0;
        if (lane == leader) bpos = atomicAdd(&sh_cnt, __popcll(mask));
        bpos = __shfl(bpos, leader);
        if (psel) {
          int pos = bpos + __popcll(mask & ((1ULL << lane) - 1ULL));
          if (pos < CAP) buf[pos] = k;
        }
      }
    }
    __syncthreads();
    int Mr = sh_cnt;
    if (Mr > CAP) Mr = CAP;
    if (Mr == 0) break;  // defensive
    // EXACT f64 rescore of selected rows (bit-identical to R5/R6 pipeline)
    if (tid < Mr) {
      u64 ak = buf[tid];
      int cl = (int)(ak & 0x1FULL);
      int p = 16383 - (int)((ak >> 10) & 0x3FFFULL);
      const float* crow = confb + (long long)p * NCLS;
      double m = (double)crow[0];
#pragma unroll
      for (int j = 1; j < NCLS; ++j) m = fmax(m, (double)crow[j]);
      double sum = 0.0, best = -1.0;
#pragma unroll
      for (int j = 0; j < NCLS; ++j) {
        double ej = exp_fast((double)crow[j] - m);
        sum += ej;
        if (j >= 1 && ej > best) best = ej;  // value only; cl fixed by argmax
      }
      double score = best / sum;
      u64 sb = (u64)__double_as_longlong(score);
      ebuf[tid] = ((sb >> 24) << 24) | ((u64)(16383 - p) << 10) | (u64)cl;
    }
    __syncthreads();
    // rank sort on exact keys (unique): buf2[rank] = ekey, descending
    if (tid < Mr) {
      u64 ka = ebuf[tid];
      int ra = 0;
      for (int i = 0; i < Mr; ++i) ra += (ebuf[i] > ka);  // LDS broadcast
      buf2[ra] = ka;
    }
    if (tid < KW) { Ash[tid] = 0ULL; KFsh[tid] = 0ULL; }
    __syncthreads();
    const int nA0 = sh_nA;
    // decode candidates on demand (bit-identical f64 ops)
    if (tid < Mr) {
      const int t = tid;
      u64 k = buf2[t];
      int cl = (int)(k & 0x1FULL);
      int p = 16383 - (int)((k >> 10) & 0x3FFFULL);
      float4 l = loc4[p];
      float4 pr = pr4[p];
      double cx = (double)pr.x + (double)l.x * 0.1 * (double)pr.z;
      double cy = (double)pr.y + (double)l.y * 0.1 * (double)pr.w;
      double w = (double)pr.z * exp_fast((double)l.z * 0.2);
      double h = (double)pr.w * exp_fast((double)l.w * 0.2);
      float x1 = (float)(cx - w * 0.5), y1 = (float)(cy - h * 0.5);
      float x2 = (float)(cx + w * 0.5), y2 = (float)(cy + h * 0.5);
      cbox[t] = make_float4(x1, y1, x2, y2);
      car[t] = (x2 - x1) * (y2 - y1);
      ccl[t] = cl;
    }
    __syncthreads();
    // pre-round suppression vs already-accepted (rounds >= 2 only)
    if (nA0 > 0 && tid < Mr) {
      const int t = tid;
      float4 my = cbox[t];
      float mar = car[t];
      int mcl = ccl[t];
      bool sup = false;
      for (int a = 0; a < nA0; ++a) {
        if (acl[a] == mcl) {
          float4 ab = abox[a];
          float ix1 = fmaxf(ab.x, my.x), iy1 = fmaxf(ab.y, my.y);
          float ix2 = fminf(ab.z, my.z), iy2 = fminf(ab.w, my.w);
          float inter = fmaxf(ix2 - ix1, 0.f) * fmaxf(iy2 - iy1, 0.f);
          if (inter > 0.45f * (aar[a] + mar - inter)) sup = true;
        }
      }
      if (sup) atomicOr(&Ash[t >> 6], 1ULL << (t & 63));
    }
    // kill-mask matrix over (candidate t, 64-wide segment): wave-uniform seg
    for (int idx = tid; idx < KW * 512; idx += T) {
      const int seg = idx >> 9;
      const int t = idx & 511;
      if (t < Mr) {
        const int i0 = seg * 64;
        int i1 = i0 + 64;
        if (i1 > Mr) i1 = Mr;
        u64 mm = 0ULL;
        if (i1 > t) {
          float4 my = cbox[t];
          float mar = car[t];
          int mcl = ccl[t];
          int is = (i0 > t + 1) ? i0 : (t + 1);
          for (int i = is; i < i1; ++i) {
            if (ccl[i] == mcl) {
              float4 cb = cbox[i];
              float ix1 = fmaxf(my.x, cb.x), iy1 = fmaxf(my.y, cb.y);
              float ix2 = fminf(my.z, cb.z), iy2 = fminf(my.w, cb.w);
              float inter = fmaxf(ix2 - ix1, 0.f) * fmaxf(iy2 - iy1, 0.f);
              if (inter > 0.45f * (mar + car[i] - inter))
                mm |= 1ULL << (i - i0);
            }
          }
        }
        KILL[t * KW + seg] = mm;
        if (mm) atomicOr(&KFsh[t >> 6], 1ULL << (t & 63));
      }
    }
    __syncthreads();
    // uniform serial resolve on wave 0 (registers; LDS row load only on kill)
    if (tid < 64) {
      u64 A0, A1, A2, A3, A4, A5;
      {
        u64 v[KW];
#pragma unroll
        for (int w = 0; w < KW; ++w) {
          int rem = Mr - 64 * w;
          u64 vm = (rem >= 64) ? ~0ULL : (rem <= 0 ? 0ULL : ((1ULL << rem) - 1ULL));
          v[w] = vm & ~Ash[w];
        }
        A0 = v[0]; A1 = v[1]; A2 = v[2]; A3 = v[3]; A4 = v[4]; A5 = v[5];
      }
      u64 C0 = 0, C1 = 0, C2 = 0, C3 = 0, C4 = 0, C5 = 0;
      int nacc = nA0;
      bool full = false;
#define KILLUPD(cidx) do { const u64* kc = &KILL[(cidx) * KW];      \
      A0 &= ~kc[0]; A1 &= ~kc[1]; A2 &= ~kc[2];                     \
      A3 &= ~kc[3]; A4 &= ~kc[4]; A5 &= ~kc[5]; } while (0)
#define RESW(w, Aw, Cw) if (!full) {                                \
      const u64 KFw = KFsh[w];                                      \
      int lim = Mr - (w) * 64; if (lim > 64) lim = 64;              \
      for (int q = 0; q < lim; ++q) {                               \
        if ((Aw >> q) & 1ULL) {                                     \
          Cw |= 1ULL << q; ++nacc;                                  \
          if (nacc == TOPK) { full = true; break; }                 \
          if ((KFw >> q) & 1ULL) KILLUPD((w) * 64 + q);             \
        } } }
      RESW(0, A0, C0)
      RESW(1, A1, C1)
      RESW(2, A2, C2)
      RESW(3, A3, C3)
      RESW(4, A4, C4)
      RESW(5, A5, C5)
#undef RESW
#undef KILLUPD
      if (tid == 0) {
        ACCsh[0] = C0; ACCsh[1] = C1; ACCsh[2] = C2;
        ACCsh[3] = C3; ACCsh[4] = C4; ACCsh[5] = C5;
        sh_nA = nacc;
      }
    }
    __syncthreads();
    // lane-parallel output of accepted candidates
    if (tid < Mr) {
      const int t = tid;
      const int w = t >> 6, q = t & 63;
      const u64 accw = ACCsh[w];
      if ((accw >> q) & 1ULL) {
        int rank = nA0;
#pragma unroll
        for (int w2 = 0; w2 < KW; ++w2)
          if (w2 < w) rank += __popcll(ACCsh[w2]);
        rank += __popcll(accw & ((q == 0) ? 0ULL : ((1ULL << q) - 1ULL)));
        float4 bx = cbox[t];
        float sc = (float)__longlong_as_double((long long)((buf2[t] >> 24) << 24));
        float* o = outb + rank * 6;
        o[0] = bx.x; o[1] = bx.y; o[2] = bx.z; o[3] = bx.w;
        o[4] = sc; o[5] = (float)ccl[t];
        abox[rank] = bx; aar[rank] = car[t]; acl[rank] = ccl[t];
      }
    }
    __syncthreads();
    if (sh_nA >= TOPK) break;
    if (total - Mr <= 0) break;  // pool exhausted
  }
  // zero-fill rows [nA, TOPK)
  const int nAf = sh_nA;
  for (int i = nAf * 6 + tid; i < TOPK * 6; i += T) outb[i] = 0.0f;
}

extern "C" void kernel_launch(void* const* d_in, const int* in_sizes, int n_in,
                              void* d_out, int out_size, void* d_ws,
                              size_t ws_size, hipStream_t stream) {
  const float* loc = (const float*)d_in[0];    // B*P*4
  const float* conf = (const float*)d_in[1];   // B*P*21
  const float* prior = (const float*)d_in[2];  // P*4
  float* out = (float*)d_out;                  // B*200*6

  u64* keys = (u64*)d_ws;  // 8,941,568 B

  const int nrows_blocks = (BATCH * NPRIOR) / 256;  // 4366 exact
  prep_kernel<<<nrows_blocks, 256, 0, stream>>>(conf, keys);
  nms_kernel<<<BATCH, T, 0, stream>>>(loc, conf, prior, keys, out);
}

// Round 8
// 207.032 us; speedup vs baseline: 11.9082x; 1.0200x over previous
//
#include <hip/hip_runtime.h>

// Detect (SSD post-process). B=128 P=8732 C=21 TOP_K=200 CONF=0.01 NMS=0.45
//
// prep (4366 blocks x 256): stage 256 conf rows via float4 -> approx f32
//   softmax score (HW v_exp_f32) -> key u64 (f32 bits | idx-desc | cls) -> ws.
// nms (128 blocks x 1024, one per batch): monotone 12-bit radix select
//   (key bits 57..46) -> ballot compact -> EXACT f64 rescore of <=384 selected
//   rows (bit-identical decisions to R5..R7) -> rank sort -> kill-mask matrix
//   -> uniform resolve -> lane-parallel output. Round loop for correctness.
//
// R8 change: phase-B buffers are DISTINCT __shared__ arrays (R5..R7 carved
// them from one char pool[] -> compiler couldn't disprove aliasing ->
// serialized every LDS load against stores in the rank-sort/kill-mask loops).
// Plus manual unrolling for load pipelining; ldexp -> exact 2^n multiply.
//
// ws: keys u64[B*P] = 8,941,568 B

typedef unsigned long long u64;

#define BATCH 128
#define NPRIOR 8732
#define NCLS 21
#define TOPK 200
#define T 1024
#define TARGET 256
#define CAP 384
#define NBIN 4096
#define KW 6

__device__ __forceinline__ double exp_fast(double x) {
  // exp for |x| < ~50, rel err < 1e-14. 2^n via exact bit-built multiply
  // (n in [-74,74] -> biased exp in [949,1097], no denormals; exact, so
  // results are bit-identical to the ldexp version validated R3..R7).
  const double LOG2E = 1.4426950408889634;
  const double LN2_HI = 6.93147180369123816490e-01;
  const double LN2_LO = 1.90821492927058770002e-10;
  double n = rint(x * LOG2E);
  double r = fma(-n, LN2_HI, x);
  r = fma(-n, LN2_LO, r);
  double p = 2.505210838544172e-08;
  p = fma(p, r, 2.755731922398589e-07);
  p = fma(p, r, 2.7557319223985893e-06);
  p = fma(p, r, 2.48015873015873e-05);
  p = fma(p, r, 1.984126984126984e-04);
  p = fma(p, r, 1.388888888888889e-03);
  p = fma(p, r, 8.333333333333333e-03);
  p = fma(p, r, 4.1666666666666664e-02);
  p = fma(p, r, 1.6666666666666666e-01);
  p = fma(p, r, 0.5);
  p = fma(p, r, 1.0);
  p = fma(p, r, 1.0);
  double scale = __longlong_as_double(((long long)(1023 + (int)n)) << 52);
  return p * scale;
}

__global__ __launch_bounds__(256) void prep_kernel(
    const float* __restrict__ conf, u64* __restrict__ keys) {
  __shared__ __align__(16) float srow[256 * NCLS];  // 21504 B
  const int tid = threadIdx.x;
  const long long R0 = (long long)blockIdx.x * 256;
  const float4* src = (const float4*)(conf + R0 * NCLS);
  float4* dst = (float4*)srow;
  for (int k = tid; k < 1344; k += 256) dst[k] = src[k];
  __syncthreads();

  const float* row = srow + tid * NCLS;
  float m = row[0];
#pragma unroll
  for (int j = 1; j < NCLS; ++j) m = fmaxf(m, row[j]);
  float sum = __expf(row[0] - m);
  float bestr = row[1];
  float beste = __expf(row[1] - m);
  sum += beste;
  int bi = 1;
#pragma unroll
  for (int j = 2; j < NCLS; ++j) {
    float rv = row[j];
    float ej = __expf(rv - m);
    sum += ej;
    if (rv > bestr) { bestr = rv; bi = j; beste = ej; }  // first-idx ties (exact raw cmp)
  }
  float score = __fdividef(beste, sum);  // approx ok: selection only

  const long long r = R0 + tid;
  const int p = (int)(r % NPRIOR);
  u64 key = 0ULL;
  if (score > 0.01f) {
    // Scores in (0.01,2): u64 bits 63..58 constant -> bits 57..46 monotone.
    key = ((u64)__float_as_uint(score) << 32) |
          ((u64)(16383 - p) << 10) | (u64)(bi - 1);
  }
  keys[r] = key;
}

// Descending cutoff bin over hist[4096]: cut[0]=c, cut[1]=count in bins>c,
// cut[2]=count in bins>=c. wtot[16]=grand total. 3 barriers.
__device__ __forceinline__ void radix_cut(const int* hist, int tid, int tcap,
                                          int* wtot, int* cut) {
  if (tid == 0) cut[2] = 0;
  const int base = tid * 4;
  const int cs = hist[base] + hist[base + 1] + hist[base + 2] + hist[base + 3];
  const int lane = tid & 63;
  int suf = cs;  // within-wave inclusive suffix sum
#pragma unroll
  for (int off = 1; off < 64; off <<= 1) {
    int v = __shfl_down(suf, off);
    if (lane + off < 64) suf += v;
  }
  if (lane == 0) wtot[tid >> 6] = suf;
  __syncthreads();
  if (tid < 16) {  // wave 0: exclusive suffix over following waves
    int v = wtot[tid];
    int s = v;
#pragma unroll
    for (int off = 1; off < 16; off <<= 1) {
      int o = __shfl_down(s, off);
      if (tid + off < 16) s += o;
    }
    if (tid == 0) wtot[16] = s;  // grand total
    wtot[tid] = s - v;
  }
  __syncthreads();
  const int total = wtot[16];
  if (total > 0) {
    const int target = total < tcap ? total : tcap;
    const int S = suf + wtot[tid >> 6];
    const int Snext = S - cs;
    if (S >= target && Snext < target) {  // unique crossing thread
      int acc = Snext;
      for (int bn = base + 3; bn >= base; --bn) {
        acc += hist[bn];
        if (acc >= target) {
          cut[0] = bn; cut[1] = acc - hist[bn]; cut[2] = acc;
          break;
        }
      }
    }
  }
  __syncthreads();
}

__global__ __launch_bounds__(T) void nms_kernel(
    const float* __restrict__ loc, const float* __restrict__ conf,
    const float* __restrict__ prior, const u64* __restrict__ keys,
    float* __restrict__ out) {
  // DISTINCT shared arrays (no pool carving) -> alias analysis works.
  __shared__ u64 Ks[NPRIOR];        // 69,856 B
  __shared__ int hist[NBIN];        // 16,384 B
  __shared__ u64 buf[CAP];          //  3,072 B (approx keys, unordered)
  __shared__ u64 ebuf[CAP];         //  3,072 B (exact keys)
  __shared__ u64 buf2[CAP];         //  3,072 B (exact, sorted desc)
  __shared__ float4 cbox[CAP];      //  6,144 B
  __shared__ float car[CAP];        //  1,536 B
  __shared__ int ccl[CAP];          //  1,536 B
  __shared__ u64 KILL[CAP * KW];    // 18,432 B
  __shared__ int wtot[17];
  __shared__ int cut1[3], cut2[3];
  __shared__ u64 Ash[KW], KFsh[KW], ACCsh[KW];
  __shared__ float4 abox[TOPK];     //  3,200 B
  __shared__ float aar[TOPK];
  __shared__ int acl[TOPK];
  __shared__ int sh_cnt, sh_nA;
  __shared__ u64 sh_ub;
  // ~128 KB -> 1 block/CU (128 blocks; batch-parallel)

  const int tid = threadIdx.x;
  const int b = blockIdx.x;
  const float* confb = conf + (long long)b * (NPRIOR * NCLS);
  const float4* loc4 = ((const float4*)loc) + (long long)b * NPRIOR;
  const float4* pr4 = (const float4*)prior;
  float* outb = out + (long long)b * (TOPK * 6);

  for (int i = tid; i < NPRIOR; i += T) Ks[i] = keys[(long long)b * NPRIOR + i];
  if (tid == 0) { sh_nA = 0; sh_ub = ~0ULL; }
  __syncthreads();

  while (true) {
    for (int i = tid; i < NBIN; i += T) hist[i] = 0;
    __syncthreads();
    const u64 ub = sh_ub;
    // L1 histogram: approx-key bits 57..46 (monotone, ~2000 spread bins)
    for (int i = tid; i < NPRIOR; i += T) {
      u64 k = Ks[i];
      if (k && k < ub) atomicAdd(&hist[(int)((k >> 46) & 0xFFF)], 1);
    }
    __syncthreads();
    radix_cut(hist, tid, TARGET, wtot, cut1);
    const int total = wtot[16];
    int M = cut1[2];
    if (M == 0) break;  // nothing remains
    const int c1 = cut1[0];
    const int baseA = cut1[1];
    const bool need2 = (M > CAP);
    int c2 = 0;
    if (need2) {  // rare: refine within bin c1 on bits 45..34
      for (int i = tid; i < NBIN; i += T) hist[i] = 0;
      __syncthreads();
      for (int i = tid; i < NPRIOR; i += T) {
        u64 k = Ks[i];
        if (k && k < ub && (int)((k >> 46) & 0xFFF) == c1)
          atomicAdd(&hist[(int)((k >> 34) & 0xFFF)], 1);
      }
      __syncthreads();
      const int tcap2 = (total < TARGET ? total : TARGET) - baseA;
      radix_cut(hist, tid, tcap2, wtot, cut2);
      c2 = cut2[0];
      M = baseA + cut2[2];
      if (M > CAP) {  // >=129 keys in one 2^-11 rel f32 window: ~impossible
        int Md = M - hist[c2];
        if (Md > 0) { M = Md; c2 = c2 + 1; } else { M = CAP; }
      }
    }
    if (tid == 0) {
      sh_cnt = 0;
      // next-round ubound = monotone pivot (selected set == {k >= pivot})
      sh_ub = need2 ? (((u64)c1 << 46) + ((u64)c2 << 34)) : ((u64)c1 << 46);
    }
    __syncthreads();
    // compact (ballot + 1 atomic/wave); order irrelevant (rank sort later)
    for (int i = tid; i < NPRIOR; i += T) {
      u64 k = Ks[i];
      bool psel = false;
      if (k && k < ub) {
        int b1 = (int)((k >> 46) & 0xFFF);
        psel = need2 ? (b1 > c1 || (b1 == c1 && (int)((k >> 34) & 0xFFF) >= c2))
                     : (b1 >= c1);
      }
      u64 mask = __ballot(psel ? 1 : 0);
      if (mask) {
        int lane = tid & 63;
        int leader = __ffsll((unsigned long long)mask) - 1;
        int bpos = 0;
        if (lane == leader) bpos = atomicAdd(&sh_cnt, __popcll(mask));
        bpos = __shfl(bpos, leader);
        if (psel) {
          int pos = bpos + __popcll(mask & ((1ULL << lane) - 1ULL));
          if (pos < CAP) buf[pos] = k;
        }
      }
    }
    __syncthreads();
    int Mr = sh_cnt;
    if (Mr > CAP) Mr = CAP;
    if (Mr == 0) break;  // defensive
    // EXACT f64 rescore of selected rows (bit-identical to R5..R7 pipeline)
    if (tid < Mr) {
      u64 ak = buf[tid];
      int cl = (int)(ak & 0x1FULL);
      int p = 16383 - (int)((ak >> 10) & 0x3FFFULL);
      const float* crow = confb + (long long)p * NCLS;
      float cr[NCLS];
#pragma unroll
      for (int j = 0; j < NCLS; ++j) cr[j] = crow[j];  // independent loads
      double m = (double)cr[0];
#pragma unroll
      for (int j = 1; j < NCLS; ++j) m = fmax(m, (double)cr[j]);
      double sum = 0.0, best = -1.0;
#pragma unroll
      for (int j = 0; j < NCLS; ++j) {
        double ej = exp_fast((double)cr[j] - m);
        sum += ej;
        if (j >= 1 && ej > best) best = ej;  // value only; cl fixed by argmax
      }
      double score = best / sum;
      u64 sb = (u64)__double_as_longlong(score);
      ebuf[tid] = ((sb >> 24) << 24) | ((u64)(16383 - p) << 10) | (u64)cl;
    }
    __syncthreads();
    // rank sort on exact keys (unique): buf2[rank] = ekey, descending.
    // Unrolled x8 so the LDS loads pipeline (independent within a batch of 8).
    if (tid < Mr) {
      u64 ka = ebuf[tid];
      int ra = 0;
      int i = 0;
      for (; i + 8 <= Mr; i += 8) {
        u64 k0 = ebuf[i], k1 = ebuf[i + 1], k2 = ebuf[i + 2], k3 = ebuf[i + 3];
        u64 k4 = ebuf[i + 4], k5 = ebuf[i + 5], k6 = ebuf[i + 6], k7 = ebuf[i + 7];
        ra += (int)(k0 > ka) + (int)(k1 > ka) + (int)(k2 > ka) + (int)(k3 > ka) +
              (int)(k4 > ka) + (int)(k5 > ka) + (int)(k6 > ka) + (int)(k7 > ka);
      }
      for (; i < Mr; ++i) ra += (int)(ebuf[i] > ka);
      buf2[ra] = ka;
    }
    if (tid < KW) { Ash[tid] = 0ULL; KFsh[tid] = 0ULL; }
    __syncthreads();
    const int nA0 = sh_nA;
    // decode candidates on demand (bit-identical f64 ops)
    if (tid < Mr) {
      const int t = tid;
      u64 k = buf2[t];
      int cl = (int)(k & 0x1FULL);
      int p = 16383 - (int)((k >> 10) & 0x3FFFULL);
      float4 l = loc4[p];
      float4 pr = pr4[p];
      double cx = (double)pr.x + (double)l.x * 0.1 * (double)pr.z;
      double cy = (double)pr.y + (double)l.y * 0.1 * (double)pr.w;
      double w = (double)pr.z * exp_fast((double)l.z * 0.2);
      double h = (double)pr.w * exp_fast((double)l.w * 0.2);
      float x1 = (float)(cx - w * 0.5), y1 = (float)(cy - h * 0.5);
      float x2 = (float)(cx + w * 0.5), y2 = (float)(cy + h * 0.5);
      cbox[t] = make_float4(x1, y1, x2, y2);
      car[t] = (x2 - x1) * (y2 - y1);
      ccl[t] = cl;
    }
    __syncthreads();
    // pre-round suppression vs already-accepted (rounds >= 2 only)
    if (nA0 > 0 && tid < Mr) {
      const int t = tid;
      float4 my = cbox[t];
      float mar = car[t];
      int mcl = ccl[t];
      bool sup = false;
      for (int a = 0; a < nA0; ++a) {
        if (acl[a] == mcl) {
          float4 ab = abox[a];
          float ix1 = fmaxf(ab.x, my.x), iy1 = fmaxf(ab.y, my.y);
          float ix2 = fminf(ab.z, my.z), iy2 = fminf(ab.w, my.w);
          float inter = fmaxf(ix2 - ix1, 0.f) * fmaxf(iy2 - iy1, 0.f);
          if (inter > 0.45f * (aar[a] + mar - inter)) sup = true;
        }
      }
      if (sup) atomicOr(&Ash[t >> 6], 1ULL << (t & 63));
    }
    // kill-mask matrix over (candidate t, 64-wide segment): wave-uniform seg
    for (int idx = tid; idx < KW * 512; idx += T) {
      const int seg = idx >> 9;
      const int t = idx & 511;
      if (t < Mr) {
        const int i0 = seg * 64;
        int i1 = i0 + 64;
        if (i1 > Mr) i1 = Mr;
        u64 mm = 0ULL;
        if (i1 > t) {
          float4 my = cbox[t];
          float mar = car[t];
          int mcl = ccl[t];
          int is = (i0 > t + 1) ? i0 : (t + 1);
#pragma unroll 4
          for (int i = is; i < i1; ++i) {
            if (ccl[i] == mcl) {
              float4 cb = cbox[i];
              float ix1 = fmaxf(my.x, cb.x), iy1 = fmaxf(my.y, cb.y);
              float ix2 = fminf(my.z, cb.z), iy2 = fminf(my.w, cb.w);
              float inter = fmaxf(ix2 - ix1, 0.f) * fmaxf(iy2 - iy1, 0.f);
              if (inter > 0.45f * (mar + car[i] - inter))
                mm |= 1ULL << (i - i0);
            }
          }
        }
        KILL[t * KW + seg] = mm;
        if (mm) atomicOr(&KFsh[t >> 6], 1ULL << (t & 63));
      }
    }
    __syncthreads();
    // uniform serial resolve on wave 0 (registers; LDS row load only on kill)
    if (tid < 64) {
      u64 A0, A1, A2, A3, A4, A5;
      {
        u64 v[KW];
#pragma unroll
        for (int w = 0; w < KW; ++w) {
          int rem = Mr - 64 * w;
          u64 vm = (rem >= 64) ? ~0ULL : (rem <= 0 ? 0ULL : ((1ULL << rem) - 1ULL));
          v[w] = vm & ~Ash[w];
        }
        A0 = v[0]; A1 = v[1]; A2 = v[2]; A3 = v[3]; A4 = v[4]; A5 = v[5];
      }
      u64 C0 = 0, C1 = 0, C2 = 0, C3 = 0, C4 = 0, C5 = 0;
      int nacc = nA0;
      bool full = false;
#define KILLUPD(cidx) do { const u64* kc = &KILL[(cidx) * KW];      \
      A0 &= ~kc[0]; A1 &= ~kc[1]; A2 &= ~kc[2];                     \
      A3 &= ~kc[3]; A4 &= ~kc[4]; A5 &= ~kc[5]; } while (0)
#define RESW(w, Aw, Cw) if (!full) {                                \
      const u64 KFw = KFsh[w];                                      \
      int lim = Mr - (w) * 64; if (lim > 64) lim = 64;              \
      for (int q = 0; q < lim; ++q) {                               \
        if ((Aw >> q) & 1ULL) {                                     \
          Cw |= 1ULL << q; ++nacc;                                  \
          if (nacc == TOPK) { full = true; break; }                 \
          if ((KFw >> q) & 1ULL) KILLUPD((w) * 64 + q);             \
        } } }
      RESW(0, A0, C0)
      RESW(1, A1, C1)
      RESW(2, A2, C2)
      RESW(3, A3, C3)
      RESW(4, A4, C4)
      RESW(5, A5, C5)
#undef RESW
#undef KILLUPD
      if (tid == 0) {
        ACCsh[0] = C0; ACCsh[1] = C1; ACCsh[2] = C2;
        ACCsh[3] = C3; ACCsh[4] = C4; ACCsh[5] = C5;
        sh_nA = nacc;
      }
    }
    __syncthreads();
    // lane-parallel output of accepted candidates
    if (tid < Mr) {
      const int t = tid;
      const int w = t >> 6, q = t & 63;
      const u64 accw = ACCsh[w];
      if ((accw >> q) & 1ULL) {
        int rank = nA0;
#pragma unroll
        for (int w2 = 0; w2 < KW; ++w2)
          if (w2 < w) rank += __popcll(ACCsh[w2]);
        rank += __popcll(accw & ((q == 0) ? 0ULL : ((1ULL << q) - 1ULL)));
        float4 bx = cbox[t];
        float sc = (float)__longlong_as_double((long long)((buf2[t] >> 24) << 24));
        float* o = outb + rank * 6;
        o[0] = bx.x; o[1] = bx.y; o[2] = bx.z; o[3] = bx.w;
        o[4] = sc; o[5] = (float)ccl[t];
        abox[rank] = bx; aar[rank] = car[t]; acl[rank] = ccl[t];
      }
    }
    __syncthreads();
    if (sh_nA >= TOPK) break;
    if (total - Mr <= 0) break;  // pool exhausted
  }
  // zero-fill rows [nA, TOPK)
  const int nAf = sh_nA;
  for (int i = nAf * 6 + tid; i < TOPK * 6; i += T) outb[i] = 0.0f;
}

extern "C" void kernel_launch(void* const* d_in, const int* in_sizes, int n_in,
                              void* d_out, int out_size, void* d_ws,
                              size_t ws_size, hipStream_t stream) {
  const float* loc = (const float*)d_in[0];    // B*P*4
  const float* conf = (const float*)d_in[1];   // B*P*21
  const float* prior = (const float*)d_in[2];  // P*4
  float* out = (float*)d_out;                  // B*200*6

  u64* keys = (u64*)d_ws;  // 8,941,568 B

  const int nrows_blocks = (BATCH * NPRIOR) / 256;  // 4366 exact
  prep_kernel<<<nrows_blocks, 256, 0, stream>>>(conf, keys);
  nms_kernel<<<BATCH, T, 0, stream>>>(loc, conf, prior, keys, out);
}